// Round 5
// baseline (492.116 us; speedup 1.0000x reference)
//
#include <hip/hip_runtime.h>
#include <stdint.h>

typedef __bf16 bf16;
typedef __bf16 bf16x8 __attribute__((ext_vector_type(8)));
typedef float f32x4 __attribute__((ext_vector_type(4)));

// ---------------- async global->LDS (16B per lane) ----------------
static __device__ __forceinline__ void async16(const void* g, void* l) {
  __builtin_amdgcn_global_load_lds(
      (__attribute__((address_space(1))) void*)g,
      (__attribute__((address_space(3))) void*)l, 16, 0, 0);
}

// ---------------- merged prep: trig tables + casts + all weight transposes ----------------
// blocks [0,2048) ttrig | [2048,18432) afold | [18432,34816) cast x_dec |
// [34816,51200) cast x_enc | [51200,57344) weight transposes.
__global__ void __launch_bounds__(256) prep_all(
    const float* __restrict__ xdec, const float* __restrict__ xenc,
    bf16* __restrict__ Ttrig, bf16* __restrict__ Afold,
    bf16* __restrict__ xdec_b, bf16* __restrict__ xenc_b,
    const float* __restrict__ Wq, const float* __restrict__ Wk,
    const float* __restrict__ Wv, const float* __restrict__ Wo,
    const float* __restrict__ W1, const float* __restrict__ W2,
    bf16* __restrict__ BtQ, bf16* __restrict__ BtK, bf16* __restrict__ WvT,
    bf16* __restrict__ WoT, bf16* __restrict__ W1T, bf16* __restrict__ W2T) {
  __shared__ bf16 tile[32][33];
  int id = blockIdx.x;
  if (id < 2048) {                     // Ttrig[1024][512]
    int idx = id * 256 + threadIdx.x;
    int d = idx & 511, jp = idx >> 9;
    int jj = jp >> 1, p = jp & 1;
    int t = (d * jj) & 511;
    float ang = (float)t * (6.283185307179586f / 512.0f);
    Ttrig[idx] = (bf16)(p ? sinf(ang) : cosf(ang));
  } else if (id < 18432) {             // Afold[2048][2048]
    int idx = (id - 2048) * 256 + threadIdx.x;
    int k = idx & 2047, k1 = idx >> 11;
    int s = (k < 1025) ? k : (k - 1024);
    int t = (k1 * s) & 2047;
    float ang = (float)t * (6.283185307179586f / 2048.0f);
    Afold[idx] = (bf16)((k < 1025) ? cosf(ang) : -sinf(ang));
  } else if (id < 34816) {
    int i = (id - 18432) * 256 + threadIdx.x;
    xdec_b[i] = (bf16)xdec[i];
  } else if (id < 51200) {
    int i = (id - 34816) * 256 + threadIdx.x;
    xenc_b[i] = (bf16)xenc[i];
  } else {
    int id2 = id - 51200;
    int kind = id2 >> 10, t = id2 & 1023;
    const float* in; bf16* out; int R, C, rt, ct;
    bool operm = false, iperm = false;
    if (kind == 0)      { in = Wq; out = BtQ; R = 2048; C = 512; rt = t >> 4; ct = t & 15; iperm = true; }
    else if (kind == 1) { in = Wk; out = BtK; R = 2048; C = 512; rt = t >> 4; ct = t & 15; iperm = true; }
    else if (kind == 2) {
      int zz = t >> 8, tt = t & 255;
      in = Wv + (long)zz * 262144; out = WvT + (long)zz * 262144;
      R = 512; C = 512; rt = tt >> 4; ct = tt & 15;
    }
    else if (kind == 3) { in = Wo; out = WoT; R = 2048; C = 512; rt = t >> 4; ct = t & 15; operm = true; }
    else if (kind == 4) { in = W1; out = W1T; R = 512; C = 2048; rt = t >> 6; ct = t & 63; }
    else                { in = W2; out = W2T; R = 2048; C = 512; rt = t >> 4; ct = t & 15; }
    int c0 = ct * 32, r0 = rt * 32;
    int tx = threadIdx.x & 31, ty = threadIdx.x >> 5;
#pragma unroll
    for (int i = 0; i < 32; i += 8) {
      int r = r0 + ty + i;
      int rr = operm ? (((r & 511) << 2) | (r >> 9)) : r;   // Wo: k'=h*512+e <- row e*4+h
      tile[ty + i][tx] = (bf16)in[(long)rr * C + (c0 + tx)];
    }
    __syncthreads();
#pragma unroll
    for (int i = 0; i < 32; i += 8) {
      int cc = c0 + ty + i, rr = r0 + tx;
      if (iperm)   // Bt row n = 4e+h from Wq/Wk row h*512+din
        out[((long)(4 * cc + (rr >> 9)) << 9) + (rr & 511)] = tile[tx][ty + i];
      else
        out[(long)cc * R + rr] = tile[tx][ty + i];
    }
  }
}

// Fold Yt [4][512][4096] (k = p*2048+s) -> Yf [4][512][2048] via s <-> 2048-s symmetry.
__global__ void __launch_bounds__(256) fold_y(const bf16* __restrict__ Yt,
                                              bf16* __restrict__ Yf) {
  int idx = blockIdx.x * 256 + threadIdx.x;
  int k = idx & 2047;
  int j = (idx >> 11) & 511;
  int b = idx >> 20;
  const bf16* yin = Yt + (long)b * 2097152 + (long)j * 4096;
  float v;
  if (k < 1025) {
    if (k == 0) v = (float)yin[0];
    else if (k == 1024) v = (float)yin[1024];
    else v = (float)yin[k] + (float)yin[2048 - k];
  } else {
    int s = k - 1024;
    v = (float)yin[2048 + s] - (float)yin[2048 + 2048 - s];
  }
  Yf[(long)b * 1048576 + (long)j * 2048 + k] = (bf16)v;
}

// ---------------- head softmax pass ----------------
// blocks [0,16384): Q -> qs[b,h,s,e]; [16384,17408): K -> ksT[b,h,d,s] via LDS transpose
__global__ void __launch_bounds__(256) softmax_qk(
    const bf16* __restrict__ qlog, bf16* __restrict__ qs,
    const bf16* __restrict__ klog, bf16* __restrict__ ksT) {
  __shared__ bf16 lds[4 * 64 * 64];   // [h][e][swizzled s]
  const int bid = blockIdx.x, t = threadIdx.x;
  if (bid < 16384) {
    int idx = bid * 256 + t;
    int e = idx & 511, s = (idx >> 9) & 2047, b = idx >> 20;
    bf16 raw[4] __attribute__((aligned(8)));
    *(uint2*)raw = *(const uint2*)(qlog + ((long)(b * 2048 + s) * 2048 + 4 * e));
    float v0 = (float)raw[0], v1 = (float)raw[1], v2 = (float)raw[2], v3 = (float)raw[3];
    float m = fmaxf(fmaxf(v0, v1), fmaxf(v2, v3));
    float e0 = expf(v0 - m), e1 = expf(v1 - m), e2 = expf(v2 - m), e3 = expf(v3 - m);
    float rs = 1.0f / (e0 + e1 + e2 + e3);
    long base = ((long)(b * 4) * 2048 + s) * 512 + e;   // h stride = 1048576
    qs[base] = (bf16)(e0 * rs);
    qs[base + 1048576] = (bf16)(e1 * rs);
    qs[base + 2097152] = (bf16)(e2 * rs);
    qs[base + 3145728] = (bf16)(e3 * rs);
  } else {
    int tb = bid - 16384;            // 4b x 32 s-tiles x 8 e-tiles
    int b = tb >> 8, rem = tb & 255;
    int s0 = (rem >> 3) << 6, e0 = (rem & 7) << 6;
    int te = t & 63, tr = t >> 6;
#pragma unroll
    for (int i = 0; i < 16; ++i) {
      int s = tr + (i << 2);
      bf16 raw[4] __attribute__((aligned(8)));
      *(uint2*)raw = *(const uint2*)(klog + ((long)(b * 2048 + s0 + s) * 2048 + 4 * (e0 + te)));
      float v0 = (float)raw[0], v1 = (float)raw[1], v2 = (float)raw[2], v3 = (float)raw[3];
      float m = fmaxf(fmaxf(v0, v1), fmaxf(v2, v3));
      float x0 = expf(v0 - m), x1 = expf(v1 - m), x2 = expf(v2 - m), x3 = expf(v3 - m);
      float rs = 1.0f / (x0 + x1 + x2 + x3);
      int cp = ((((s >> 2) ^ (te & 15)) << 2) | (s & 3));
      int base = te * 64 + cp;
      lds[base] = (bf16)(x0 * rs);
      lds[4096 + base] = (bf16)(x1 * rs);
      lds[8192 + base] = (bf16)(x2 * rs);
      lds[12288 + base] = (bf16)(x3 * rs);
    }
    __syncthreads();
    int sc = t & 15, r = t >> 4;
#pragma unroll
    for (int i = 0; i < 16; ++i) {
      int he = r + (i << 4);         // 0..255
      int h = he >> 6, e = he & 63;
      int cp = (sc ^ (e & 15)) << 2;
      bf16 tmp[4] __attribute__((aligned(8)));
      *(uint2*)tmp = *(const uint2*)&lds[h * 4096 + e * 64 + cp];
      *(uint2*)(ksT + ((long)(b * 4 + h) * 512 + e0 + e) * 2048 + s0 + (sc << 2)) =
          *(const uint2*)tmp;
    }
  }
}

// ---------------- LayerNorm over D=512: out = g*(A+B - mu)*rstd + be ----------------
template <int WRITE_BF16, int WRITE_F32>
__global__ void __launch_bounds__(256) ln_kernel(
    const float* __restrict__ A, const float* __restrict__ Bv,
    const float* __restrict__ g, const float* __restrict__ be,
    bf16* __restrict__ outb, float* __restrict__ outf) {
  const int row = blockIdx.x, t = threadIdx.x;
  const long base = (long)row * 512;
  float v0 = A[base + t] + Bv[base + t];
  float v1 = A[base + t + 256] + Bv[base + t + 256];
  float s = v0 + v1, q = v0 * v0 + v1 * v1;
#pragma unroll
  for (int off = 32; off > 0; off >>= 1) {
    s += __shfl_down(s, off);
    q += __shfl_down(q, off);
  }
  __shared__ float red[8];
  const int wv = t >> 6, ln = t & 63;
  if (ln == 0) { red[wv] = s; red[wv + 4] = q; }
  __syncthreads();
  float S = red[0] + red[1] + red[2] + red[3];
  float Q = red[4] + red[5] + red[6] + red[7];
  float mu = S * (1.0f / 512.0f);
  float var = Q * (1.0f / 512.0f) - mu * mu;
  float rstd = rsqrtf(var + 1e-5f);
  float o0 = g[t] * (v0 - mu) * rstd + be[t];
  float o1 = g[t + 256] * (v1 - mu) * rstd + be[t + 256];
  if (WRITE_BF16) { outb[base + t] = (bf16)o0; outb[base + t + 256] = (bf16)o1; }
  if (WRITE_F32)  { outf[base + t] = o0; outf[base + t + 256] = o1; }
}

// ---------------- GEMM: C = A[M,K] * Bt[N,K]^T -----------------------------------------
// DOUBLE-BUFFERED K-loop: per iter  barrier -> issue async prefetch(tile i+1, buf p^1)
// -> MFMA(tile i, buf p). The compiler's pre-barrier vmcnt drain then lands AFTER a full
// compute phase covered the load latency (one barrier/iter).
// SWIZ: 0 plain; 1 group-by-y (flat%8==y%8); 2 group-by-z. gin = blocks per group.
// ADDR_MODE: 0 plain (sCz*z); 2 attn out to cat[b,s,h*512+col] (z=b*4+h);
// 3 V transposed scatter [B,H,D,S] (z=head, 8B packed); 6 merged K|V (cols<2048: klog
// [b,s,4e+h] -> Cout; cols>=2048: V transposed -> Cout2, bias2).
// HAS_BIAS: 0 none, 1 bias[sBiasz*z+col], 2 head-interleaved bias[(col&3)*512+(col>>2)].
template <int BN, int ADDR_MODE, int HAS_BIAS, int DO_SELU, int F32OUT, int SWIZ>
__global__ void __launch_bounds__(256, 2) gemm_bt(
    const bf16* __restrict__ A, const bf16* __restrict__ Bt,
    const float* __restrict__ bias, const float* __restrict__ bias2,
    void* __restrict__ Cout, void* __restrict__ Cout2,
    int N, int K, long sAz, long sBz, long sBiasz, long sCz,
    int gx, int gy, int gin) {
  __shared__ __align__(16) bf16 lA[2][128 * 64];
  __shared__ __align__(16) bf16 lB[2][BN * 64];
  int x, y, z;
  {
    int id = blockIdx.x;
    if (SWIZ == 0) {
      x = id % gx; int t2 = id / gx; y = t2 % gy; z = t2 / gy;
    } else {
      int xcd = id & 7, r = id >> 3;
      int inner = r % gin, G = xcd + 8 * (r / gin);
      if (SWIZ == 1) { y = G; x = inner % gx; z = inner / gx; }
      else           { z = G; x = inner % gx; y = inner / gx; }
    }
  }
  A  += sAz * z;
  Bt += sBz * z;
  const int m0 = y * 128, n0 = x * BN;
  const int t = threadIdx.x;
  const int lane = t & 63, wave = t >> 6;
  const int srow = t >> 3;
  const int pch  = t & 7;
  const int lch  = pch ^ (srow & 7);   // XOR bank swizzle (global-side)
  const bf16* Ag = A  + (long)(m0 + srow) * K + lch * 8;
  const bf16* Bg = Bt + (long)(n0 + srow) * K + lch * 8;
  const int loff = srow * 64 + pch * 8;
  constexpr int MI = (BN == 128) ? 4 : 2;
  const int wm = (BN == 128) ? (wave >> 1) * 64 : wave * 32;
  const int wn = (BN == 128) ? (wave & 1) * 64 : 0;
  const int fr = lane & 15, fq = lane >> 4;

  f32x4 acc[MI][4] = {};

  // prologue: stage tile 0 into buffer 0
#pragma unroll
  for (int i = 0; i < 4; ++i)
    async16(Ag + (long)(32 * i) * K, &lA[0][loff + 32 * i * 64]);
#pragma unroll
  for (int i = 0; i < BN / 32; ++i)
    async16(Bg + (long)(32 * i) * K, &lB[0][loff + 32 * i * 64]);

  int p = 0;
  for (int k0 = 0; k0 < K; k0 += 64) {
    __syncthreads();   // compiler drains vmcnt before s_barrier -> buf p ready
    if (k0 + 64 < K) {           // prefetch tile i+1 into buf p^1 (in flight during MFMA)
#pragma unroll
      for (int i = 0; i < 4; ++i)
        async16(Ag + k0 + 64 + (long)(32 * i) * K, &lA[p ^ 1][loff + 32 * i * 64]);
#pragma unroll
      for (int i = 0; i < BN / 32; ++i)
        async16(Bg + k0 + 64 + (long)(32 * i) * K, &lB[p ^ 1][loff + 32 * i * 64]);
    }
#pragma unroll
    for (int kk = 0; kk < 2; ++kk) {
      bf16x8 av[MI], bfrag[4];
#pragma unroll
      for (int mi = 0; mi < MI; ++mi) {
        int r = wm + mi * 16 + fr;
        int c = (kk * 4 + fq) ^ (r & 7);
        av[mi] = *(const bf16x8*)&lA[p][r * 64 + c * 8];
      }
#pragma unroll
      for (int ni = 0; ni < 4; ++ni) {
        int r = wn + ni * 16 + fr;
        int c = (kk * 4 + fq) ^ (r & 7);
        bfrag[ni] = *(const bf16x8*)&lB[p][r * 64 + c * 8];
      }
#pragma unroll
      for (int mi = 0; mi < MI; ++mi)
#pragma unroll
        for (int ni = 0; ni < 4; ++ni)
          acc[mi][ni] = __builtin_amdgcn_mfma_f32_16x16x32_bf16(
              av[mi], bfrag[ni], acc[mi][ni], 0, 0, 0);
    }
    p ^= 1;
  }

  // epilogue: C/D layout col = lane&15, row = (lane>>4)*4 + reg
#pragma unroll
  for (int mi = 0; mi < MI; ++mi) {
#pragma unroll
    for (int ni = 0; ni < 4; ++ni) {
      const int col = n0 + wn + ni * 16 + fr;
      float bias_v = 0.0f;
      if (HAS_BIAS == 1) bias_v = bias[sBiasz * z + col];
      if (HAS_BIAS == 2) bias_v = bias[(col & 3) * 512 + (col >> 2)];
      if (ADDR_MODE == 3) {
        const int row0 = m0 + wm + mi * 16 + fq * 4;
        const int b = row0 >> 11, s = row0 & 2047;
        bf16 tmp[4] __attribute__((aligned(8)));
#pragma unroll
        for (int r = 0; r < 4; ++r) tmp[r] = (bf16)(acc[mi][ni][r] + bias_v);
        long addr = ((long)((b << 2) + z) * 512 + col) * 2048 + s;
        *(uint2*)((bf16*)Cout + addr) = *(const uint2*)tmp;
      } else if (ADDR_MODE == 6) {
        const int row0 = m0 + wm + mi * 16 + fq * 4;
        if (n0 < 2048) {          // K logits, plain coalesced (row = b*2048+s)
          float bv2 = bias[(col & 3) * 512 + (col >> 2)];
#pragma unroll
          for (int r = 0; r < 4; ++r)
            ((bf16*)Cout)[(long)(row0 + r) * 2048 + col] =
                (bf16)(acc[mi][ni][r] + bv2);
        } else {                  // V, transposed packed store
          const int c2 = col - 2048;
          float bv2 = bias2[c2];
          const int b = row0 >> 11, s = row0 & 2047;
          bf16 tmp[4] __attribute__((aligned(8)));
#pragma unroll
          for (int r = 0; r < 4; ++r) tmp[r] = (bf16)(acc[mi][ni][r] + bv2);
          long addr = ((long)((b << 2) + (c2 >> 9)) * 512 + (c2 & 511)) * 2048 + s;
          *(uint2*)((bf16*)Cout2 + addr) = *(const uint2*)tmp;
        }
      } else {
#pragma unroll
        for (int r = 0; r < 4; ++r) {
          const int row = m0 + wm + mi * 16 + fq * 4 + r;
          float v = acc[mi][ni][r] + bias_v;
          if (DO_SELU) v = v > 0.0f ? 1.0507009873554805f * v
                                    : 1.7580993408473766f * (expf(v) - 1.0f);
          long addr;
          if (ADDR_MODE == 0) {
            addr = sCz * z + (long)row * N + col;
          } else {                               // mode 2: z=b*4+h; cat[b,s,h*512+col]
            int b = z >> 2, h = z & 3;
            addr = ((long)(b * 2048 + row)) * 2048 + h * 512 + col;
          }
          if (F32OUT) ((float*)Cout)[addr] = v;
          else        ((bf16*)Cout)[addr] = (bf16)v;
        }
      }
    }
  }
}

// ---------------- launcher ----------------
extern "C" void kernel_launch(void* const* d_in, const int* in_sizes, int n_in,
                              void* d_out, int out_size, void* d_ws, size_t ws_size,
                              hipStream_t stream) {
  (void)in_sizes; (void)n_in; (void)out_size; (void)ws_size;
  const float* x_enc = (const float*)d_in[0];
  const float* x_dec = (const float*)d_in[1];
  const float* Wq = (const float*)d_in[2];
  const float* bq = (const float*)d_in[3];
  const float* Wk = (const float*)d_in[4];
  const float* bk = (const float*)d_in[5];
  const float* Wv = (const float*)d_in[6];
  const float* bv = (const float*)d_in[7];
  const float* Wo = (const float*)d_in[8];
  const float* bo = (const float*)d_in[9];
  const float* g1 = (const float*)d_in[10];
  const float* be1 = (const float*)d_in[11];
  const float* g2 = (const float*)d_in[12];
  const float* be2 = (const float*)d_in[13];
  const float* W1 = (const float*)d_in[14];
  const float* b1 = (const float*)d_in[15];
  const float* W2 = (const float*)d_in[16];
  const float* b2 = (const float*)d_in[17];
  const float* g3 = (const float*)d_in[18];
  const float* be3 = (const float*)d_in[19];

  char* ws = (char*)d_ws;
  const size_t MB = 1u << 20;
  // time-disjoint aliasing, peak 229 MiB
  bf16*  qlog   = (bf16*) (ws + 0);        // Q logits -> dead after softmax
  bf16*  cat    = (bf16*) (ws + 0);        // out-GEMM out
  bf16*  klog   = (bf16*) (ws + 32 * MB);  // K logits -> dead after softmax
  bf16*  midb   = (bf16*) (ws + 32 * MB);  // W1 out
  bf16*  qs     = (bf16*) (ws + 64 * MB);  // softmax Q -> dead after out-GEMM
  float* ff_f   = (float*)(ws + 64 * MB);  // W2 out
  bf16*  ksT    = (bf16*) (ws + 96 * MB);  // softmax K -> dead after gc-GEMM
  float* attn_f = (float*)(ws + 96 * MB);  // Wo out
  bf16*  vsT    = (bf16*) (ws + 128 * MB); // V out -> dead after gc-GEMM
  float* x2_f   = (float*)(ws + 128 * MB); // LN2 out (fp32)
  bf16*  x2_b   = (bf16*) (ws + 144 * MB); // LN2 out (bf16)
  float* xd_f   = (float*)(ws + 160 * MB); // LN1 out (fp32)
  bf16*  Yt     = (bf16*) (ws + 176 * MB); // stage-1 DFT -> dead after fold
  float* xf_f   = (float*)(ws + 176 * MB); // Afold out -> dead after LN1
  bf16*  xdec_b = (bf16*) (ws + 192 * MB); // dead after Yt GEMM
  bf16*  Yfold  = (bf16*) (ws + 192 * MB); // fold out -> dead after Afold GEMM
  bf16*  xd_b   = (bf16*) (ws + 192 * MB); // LN1 bf16 -> dead after Q GEMM
  bf16*  gcT    = (bf16*) (ws + 192 * MB); // gc out -> dead after out GEMM
  bf16*  xenc_b = (bf16*) (ws + 200 * MB);
  bf16*  Ttrig  = (bf16*) (ws + 208 * MB);
  bf16*  Afold  = (bf16*) (ws + 209 * MB);
  bf16*  BtQ    = (bf16*) (ws + 217 * MB);
  bf16*  BtK    = (bf16*) (ws + 219 * MB); // BtK + WvT form contiguous 4096x512 B^T
  bf16*  WvT    = (bf16*) (ws + 221 * MB);
  bf16*  WoT    = (bf16*) (ws + 223 * MB);
  bf16*  W1T    = (bf16*) (ws + 225 * MB);
  bf16*  W2T    = (bf16*) (ws + 227 * MB); // end 229 MiB

  // --- prep (one launch) ---
  prep_all<<<57344, 256, 0, stream>>>(x_dec, x_enc, Ttrig, Afold, xdec_b, xenc_b,
                                      Wq, Wk, Wv, Wo, W1, W2,
                                      BtQ, BtK, WvT, WoT, W1T, W2T);

  // --- Fourier mixing ---
  gemm_bt<128, 0, 0, 0, 0, 1><<<512, 256, 0, stream>>>(
      Ttrig, xdec_b, nullptr, nullptr, Yt, nullptr,
      2048, 512, 0L, 1048576L, 0L, 2097152L, 16, 8, 64);
  fold_y<<<16384, 256, 0, stream>>>(Yt, Yfold);
  gemm_bt<64, 0, 0, 0, 1, 1><<<512, 256, 0, stream>>>(
      Afold, Yfold, nullptr, nullptr, xf_f, nullptr,
      512, 2048, 0L, 1048576L, 0L, 1048576L, 8, 16, 32);
  ln_kernel<1, 1><<<8192, 256, 0, stream>>>(x_dec, xf_f, g1, be1, xd_b, xd_f);

  // --- attention ---
  gemm_bt<128, 0, 2, 0, 0, 1><<<1024, 256, 0, stream>>>(   // Q logits [b,s,4e+h]
      xd_b, BtQ, bq, nullptr, qlog, nullptr,
      2048, 512, 0L, 0L, 0L, 0L, 16, 64, 16);
  gemm_bt<128, 6, 0, 0, 0, 1><<<2048, 256, 0, stream>>>(   // K logits + V (merged)
      xenc_b, BtK, bk, bv, klog, vsT,
      4096, 512, 0L, 0L, 0L, 0L, 32, 64, 32);
  softmax_qk<<<17408, 256, 0, stream>>>(qlog, qs, klog, ksT);
  gemm_bt<64, 0, 0, 0, 0, 2><<<512, 256, 0, stream>>>(     // gc^T (z=b*4+h, K=2048)
      vsT, ksT, nullptr, nullptr, gcT, nullptr,
      512, 2048, 1048576L, 1048576L, 0L, 262144L, 8, 4, 32);
  gemm_bt<128, 2, 0, 0, 0, 2><<<1024, 256, 0, stream>>>(   // out = qs.gc -> cat
      qs, gcT, nullptr, nullptr, cat, nullptr,
      512, 512, 1048576L, 262144L, 0L, 0L, 4, 16, 64);
  gemm_bt<64, 0, 1, 0, 1, 1><<<512, 256, 0, stream>>>(     // attn = cat.WoP + bo
      cat, WoT, bo, nullptr, attn_f, nullptr,
      512, 2048, 0L, 0L, 0L, 0L, 8, 64, 8);
  ln_kernel<1, 1><<<8192, 256, 0, stream>>>(xd_f, attn_f, g2, be2, x2_b, x2_f);

  // --- FFN ---
  gemm_bt<128, 0, 1, 1, 0, 1><<<1024, 256, 0, stream>>>(
      x2_b, W1T, b1, nullptr, midb, nullptr,
      2048, 512, 0L, 0L, 0L, 0L, 16, 64, 16);
  gemm_bt<64, 0, 1, 0, 1, 1><<<512, 256, 0, stream>>>(
      midb, W2T, b2, nullptr, ff_f, nullptr,
      512, 2048, 0L, 0L, 0L, 0L, 8, 64, 8);
  ln_kernel<0, 1><<<8192, 256, 0, stream>>>(x2_f, ff_f, g3, be3, nullptr, (float*)d_out);
}

// Round 6
// 471.270 us; speedup vs baseline: 1.0442x; 1.0442x over previous
//
#include <hip/hip_runtime.h>
#include <stdint.h>

typedef __bf16 bf16;
typedef __bf16 bf16x8 __attribute__((ext_vector_type(8)));
typedef float f32x4 __attribute__((ext_vector_type(4)));

// ---------------- async global->LDS (16B per lane) ----------------
static __device__ __forceinline__ void async16(const void* g, void* l) {
  __builtin_amdgcn_global_load_lds(
      (__attribute__((address_space(1))) void*)g,
      (__attribute__((address_space(3))) void*)l, 16, 0, 0);
}

// ---------------- merged prep: trig tables + casts + all weight transposes ----------------
// blocks [0,2048) ttrig | [2048,18432) afold | [18432,34816) cast x_dec |
// [34816,51200) cast x_enc | [51200,57344) weight transposes.
__global__ void __launch_bounds__(256) prep_all(
    const float* __restrict__ xdec, const float* __restrict__ xenc,
    bf16* __restrict__ Ttrig, bf16* __restrict__ Afold,
    bf16* __restrict__ xdec_b, bf16* __restrict__ xenc_b,
    const float* __restrict__ Wq, const float* __restrict__ Wk,
    const float* __restrict__ Wv, const float* __restrict__ Wo,
    const float* __restrict__ W1, const float* __restrict__ W2,
    bf16* __restrict__ BtQ, bf16* __restrict__ BtK, bf16* __restrict__ WvT,
    bf16* __restrict__ WoTh, bf16* __restrict__ W1T, bf16* __restrict__ W2T) {
  __shared__ bf16 tile[32][33];
  int id = blockIdx.x;
  if (id < 2048) {                     // Ttrig[1024][512]
    int idx = id * 256 + threadIdx.x;
    int d = idx & 511, jp = idx >> 9;
    int jj = jp >> 1, p = jp & 1;
    int t = (d * jj) & 511;
    float ang = (float)t * (6.283185307179586f / 512.0f);
    Ttrig[idx] = (bf16)(p ? sinf(ang) : cosf(ang));
  } else if (id < 18432) {             // Afold[2048][2048]
    int idx = (id - 2048) * 256 + threadIdx.x;
    int k = idx & 2047, k1 = idx >> 11;
    int s = (k < 1025) ? k : (k - 1024);
    int t = (k1 * s) & 2047;
    float ang = (float)t * (6.283185307179586f / 2048.0f);
    Afold[idx] = (bf16)((k < 1025) ? cosf(ang) : -sinf(ang));
  } else if (id < 34816) {
    int i = (id - 18432) * 256 + threadIdx.x;
    xdec_b[i] = (bf16)xdec[i];
  } else if (id < 51200) {
    int i = (id - 34816) * 256 + threadIdx.x;
    xenc_b[i] = (bf16)xenc[i];
  } else {
    int id2 = id - 51200;
    int kind = id2 >> 10, t = id2 & 1023;
    const float* in; bf16* out; int R, C, rt, ct;
    bool iperm = false, hsel = false; int hh = 0;
    if (kind == 0)      { in = Wq; out = BtQ; R = 2048; C = 512; rt = t >> 4; ct = t & 15; iperm = true; }
    else if (kind == 1) { in = Wk; out = BtK; R = 2048; C = 512; rt = t >> 4; ct = t & 15; iperm = true; }
    else if (kind == 2) {
      int zz = t >> 8, tt = t & 255;
      in = Wv + (long)zz * 262144; out = WvT + (long)zz * 262144;
      R = 512; C = 512; rt = tt >> 4; ct = tt & 15;
    }
    else if (kind == 3) {              // WoTh[h][n][e] = Wo[4e+h][n]
      int zz = t >> 8, tt = t & 255;
      in = Wo; out = WoTh + (long)zz * 262144;
      R = 512; C = 512; rt = tt >> 4; ct = tt & 15; hsel = true; hh = zz;
    }
    else if (kind == 4) { in = W1; out = W1T; R = 512; C = 2048; rt = t >> 6; ct = t & 63; }
    else                { in = W2; out = W2T; R = 2048; C = 512; rt = t >> 4; ct = t & 15; }
    int c0 = ct * 32, r0 = rt * 32;
    int tx = threadIdx.x & 31, ty = threadIdx.x >> 5;
#pragma unroll
    for (int i = 0; i < 32; i += 8) {
      int r = r0 + ty + i;
      int rr = hsel ? (4 * r + hh) : r;
      tile[ty + i][tx] = (bf16)in[(long)rr * C + (c0 + tx)];
    }
    __syncthreads();
#pragma unroll
    for (int i = 0; i < 32; i += 8) {
      int cc = c0 + ty + i, rr = r0 + tx;
      if (iperm)   // Bt row n = 4e+h from Wq/Wk row h*512+din
        out[((long)(4 * cc + (rr >> 9)) << 9) + (rr & 511)] = tile[tx][ty + i];
      else
        out[(long)cc * R + rr] = tile[tx][ty + i];
    }
  }
}

// Fold Yt [4][512][4096] (k = p*2048+s) -> Yf [4][512][2048] via s <-> 2048-s symmetry.
__global__ void __launch_bounds__(256) fold_y(const bf16* __restrict__ Yt,
                                              bf16* __restrict__ Yf) {
  int idx = blockIdx.x * 256 + threadIdx.x;
  int k = idx & 2047;
  int j = (idx >> 11) & 511;
  int b = idx >> 20;
  const bf16* yin = Yt + (long)b * 2097152 + (long)j * 4096;
  float v;
  if (k < 1025) {
    if (k == 0) v = (float)yin[0];
    else if (k == 1024) v = (float)yin[1024];
    else v = (float)yin[k] + (float)yin[2048 - k];
  } else {
    int s = k - 1024;
    v = (float)yin[2048 + s] - (float)yin[2048 + 2048 - s];
  }
  Yf[(long)b * 1048576 + (long)j * 2048 + k] = (bf16)v;
}

// ---------------- head softmax pass ----------------
// blocks [0,16384): Q [b,s,4e+h] -> qs2[b,s,h*512+e] (in-row permute, coalesced)
// blocks [16384,17408): K -> ksT[b,h,d,s] via XOR-swizzled LDS 64x64 tile transpose
__global__ void __launch_bounds__(256) softmax_qk(
    const bf16* __restrict__ qlog, bf16* __restrict__ qs2,
    const bf16* __restrict__ klog, bf16* __restrict__ ksT) {
  __shared__ bf16 lds[4 * 64 * 64];   // [h][e][swizzled s]
  const int bid = blockIdx.x, t = threadIdx.x;
  if (bid < 16384) {
    int idx = bid * 256 + t;
    int e = idx & 511, s = (idx >> 9) & 2047, b = idx >> 20;
    bf16 raw[4] __attribute__((aligned(8)));
    *(uint2*)raw = *(const uint2*)(qlog + ((long)(b * 2048 + s) * 2048 + 4 * e));
    float v0 = (float)raw[0], v1 = (float)raw[1], v2 = (float)raw[2], v3 = (float)raw[3];
    float m = fmaxf(fmaxf(v0, v1), fmaxf(v2, v3));
    float e0 = expf(v0 - m), e1 = expf(v1 - m), e2 = expf(v2 - m), e3 = expf(v3 - m);
    float rs = 1.0f / (e0 + e1 + e2 + e3);
    long base = ((long)(b * 2048 + s)) * 2048 + e;   // h stride = 512 within row
    qs2[base] = (bf16)(e0 * rs);
    qs2[base + 512] = (bf16)(e1 * rs);
    qs2[base + 1024] = (bf16)(e2 * rs);
    qs2[base + 1536] = (bf16)(e3 * rs);
  } else {
    int tb = bid - 16384;            // 4b x 32 s-tiles x 8 e-tiles
    int b = tb >> 8, rem = tb & 255;
    int s0 = (rem >> 3) << 6, e0 = (rem & 7) << 6;
    int te = t & 63, tr = t >> 6;
#pragma unroll
    for (int i = 0; i < 16; ++i) {
      int s = tr + (i << 2);
      bf16 raw[4] __attribute__((aligned(8)));
      *(uint2*)raw = *(const uint2*)(klog + ((long)(b * 2048 + s0 + s) * 2048 + 4 * (e0 + te)));
      float v0 = (float)raw[0], v1 = (float)raw[1], v2 = (float)raw[2], v3 = (float)raw[3];
      float m = fmaxf(fmaxf(v0, v1), fmaxf(v2, v3));
      float x0 = expf(v0 - m), x1 = expf(v1 - m), x2 = expf(v2 - m), x3 = expf(v3 - m);
      float rs = 1.0f / (x0 + x1 + x2 + x3);
      int cp = ((((s >> 2) ^ (te & 15)) << 2) | (s & 3));
      int base = te * 64 + cp;
      lds[base] = (bf16)(x0 * rs);
      lds[4096 + base] = (bf16)(x1 * rs);
      lds[8192 + base] = (bf16)(x2 * rs);
      lds[12288 + base] = (bf16)(x3 * rs);
    }
    __syncthreads();
    int sc = t & 15, r = t >> 4;
#pragma unroll
    for (int i = 0; i < 16; ++i) {
      int he = r + (i << 4);         // 0..255
      int h = he >> 6, e = he & 63;
      int cp = (sc ^ (e & 15)) << 2;
      bf16 tmp[4] __attribute__((aligned(8)));
      *(uint2*)tmp = *(const uint2*)&lds[h * 4096 + e * 64 + cp];
      *(uint2*)(ksT + ((long)(b * 4 + h) * 512 + e0 + e) * 2048 + s0 + (sc << 2)) =
          *(const uint2*)tmp;
    }
  }
}

// ---------------- LayerNorm over D=512: out = g*(A+B - mu)*rstd + be ----------------
template <int WRITE_BF16, int WRITE_F32>
__global__ void __launch_bounds__(256) ln_kernel(
    const float* __restrict__ A, const float* __restrict__ Bv,
    const float* __restrict__ g, const float* __restrict__ be,
    bf16* __restrict__ outb, float* __restrict__ outf) {
  const int row = blockIdx.x, t = threadIdx.x;
  const long base = (long)row * 512;
  float v0 = A[base + t] + Bv[base + t];
  float v1 = A[base + t + 256] + Bv[base + t + 256];
  float s = v0 + v1, q = v0 * v0 + v1 * v1;
#pragma unroll
  for (int off = 32; off > 0; off >>= 1) {
    s += __shfl_down(s, off);
    q += __shfl_down(q, off);
  }
  __shared__ float red[8];
  const int wv = t >> 6, ln = t & 63;
  if (ln == 0) { red[wv] = s; red[wv + 4] = q; }
  __syncthreads();
  float S = red[0] + red[1] + red[2] + red[3];
  float Q = red[4] + red[5] + red[6] + red[7];
  float mu = S * (1.0f / 512.0f);
  float var = Q * (1.0f / 512.0f) - mu * mu;
  float rstd = rsqrtf(var + 1e-5f);
  float o0 = g[t] * (v0 - mu) * rstd + be[t];
  float o1 = g[t + 256] * (v1 - mu) * rstd + be[t + 256];
  if (WRITE_BF16) { outb[base + t] = (bf16)o0; outb[base + t + 256] = (bf16)o1; }
  if (WRITE_F32)  { outf[base + t] = o0; outf[base + t + 256] = o1; }
}

// ---------------- GEMM: C = A[M,K] * Bt[N,K]^T (single-buffer m97 K-loop) --------------
// SWIZ: 0 plain; 1 group-by-y (flat%8==y%8); 2 group-by-z. gin = blocks per group.
// ADDR_MODE: 0 plain (sCz*z); 3 V transposed scatter [B,H,D,S] (z=head, 8B packed);
// 7 gw out: z=b*4+h, Bt_b[n=row][h*512+col] i.e. addr=(b*512+row)*2048+h*512+col.
// HAS_BIAS: 0 none, 1 bias[sBiasz*z+col], 2 head-interleaved bias[(col&3)*512+(col>>2)].
// AHEAD: A += sAz*(z&3) instead of sAz*z (per-head weight selection).
template <int BN, int ADDR_MODE, int HAS_BIAS, int DO_SELU, int F32OUT, int SWIZ,
          int AHEAD = 0>
__global__ void __launch_bounds__(256, 2) gemm_bt(
    const bf16* __restrict__ A, const bf16* __restrict__ Bt,
    const float* __restrict__ bias, void* __restrict__ Cout,
    int N, int K, long sAz, long sBz, long sBiasz, long sCz,
    int gx, int gy, int gin) {
  __shared__ __align__(16) bf16 lA[128 * 64];
  __shared__ __align__(16) bf16 lB[BN * 64];
  int x, y, z;
  {
    int id = blockIdx.x;
    if (SWIZ == 0) {
      x = id % gx; int t2 = id / gx; y = t2 % gy; z = t2 / gy;
    } else {
      int xcd = id & 7, r = id >> 3;
      int inner = r % gin, G = xcd + 8 * (r / gin);
      if (SWIZ == 1) { y = G; x = inner % gx; z = inner / gx; }
      else           { z = G; x = inner % gx; y = inner / gx; }
    }
  }
  A  += AHEAD ? sAz * (z & 3) : sAz * z;
  Bt += sBz * z;
  const int m0 = y * 128, n0 = x * BN;
  const int t = threadIdx.x;
  const int lane = t & 63, wave = t >> 6;
  const int srow = t >> 3;
  const int pch  = t & 7;
  const int lch  = pch ^ (srow & 7);   // XOR bank swizzle (global-side)
  const bf16* Ag = A  + (long)(m0 + srow) * K + lch * 8;
  const bf16* Bg = Bt + (long)(n0 + srow) * K + lch * 8;
  bf16* lAp = lA + srow * 64 + pch * 8;
  bf16* lBp = lB + srow * 64 + pch * 8;
  constexpr int MI = (BN == 128) ? 4 : 2;
  const int wm = (BN == 128) ? (wave >> 1) * 64 : wave * 32;
  const int wn = (BN == 128) ? (wave & 1) * 64 : 0;
  const int fr = lane & 15, fq = lane >> 4;

  f32x4 acc[MI][4] = {};

  for (int k0 = 0; k0 < K; k0 += 64) {
    __syncthreads();
#pragma unroll
    for (int i = 0; i < 4; ++i)
      async16(Ag + k0 + (long)(32 * i) * K, lAp + 32 * i * 64);
#pragma unroll
    for (int i = 0; i < BN / 32; ++i)
      async16(Bg + k0 + (long)(32 * i) * K, lBp + 32 * i * 64);
    __syncthreads();
#pragma unroll
    for (int kk = 0; kk < 2; ++kk) {
      bf16x8 av[MI], bfrag[4];
#pragma unroll
      for (int mi = 0; mi < MI; ++mi) {
        int r = wm + mi * 16 + fr;
        int c = (kk * 4 + fq) ^ (r & 7);
        av[mi] = *(const bf16x8*)&lA[r * 64 + c * 8];
      }
#pragma unroll
      for (int ni = 0; ni < 4; ++ni) {
        int r = wn + ni * 16 + fr;
        int c = (kk * 4 + fq) ^ (r & 7);
        bfrag[ni] = *(const bf16x8*)&lB[r * 64 + c * 8];
      }
#pragma unroll
      for (int mi = 0; mi < MI; ++mi)
#pragma unroll
        for (int ni = 0; ni < 4; ++ni)
          acc[mi][ni] = __builtin_amdgcn_mfma_f32_16x16x32_bf16(
              av[mi], bfrag[ni], acc[mi][ni], 0, 0, 0);
    }
  }

  // epilogue: C/D layout col = lane&15, row = (lane>>4)*4 + reg
#pragma unroll
  for (int mi = 0; mi < MI; ++mi) {
#pragma unroll
    for (int ni = 0; ni < 4; ++ni) {
      const int col = n0 + wn + ni * 16 + fr;
      float bias_v = 0.0f;
      if (HAS_BIAS == 1) bias_v = bias[sBiasz * z + col];
      if (HAS_BIAS == 2) bias_v = bias[(col & 3) * 512 + (col >> 2)];
      if (ADDR_MODE == 3) {
        const int row0 = m0 + wm + mi * 16 + fq * 4;
        const int b = row0 >> 11, s = row0 & 2047;
        bf16 tmp[4] __attribute__((aligned(8)));
#pragma unroll
        for (int r = 0; r < 4; ++r) tmp[r] = (bf16)(acc[mi][ni][r] + bias_v);
        long addr = ((long)((b << 2) + z) * 512 + col) * 2048 + s;
        *(uint2*)((bf16*)Cout + addr) = *(const uint2*)tmp;
      } else if (ADDR_MODE == 7) {           // z=b*4+h -> Bt_b[n=row][h*512+col]
        const int b = z >> 2, h = z & 3;
#pragma unroll
        for (int r = 0; r < 4; ++r) {
          const int row = m0 + wm + mi * 16 + fq * 4 + r;
          ((bf16*)Cout)[((long)(b * 512 + row)) * 2048 + h * 512 + col] =
              (bf16)(acc[mi][ni][r] + bias_v);
        }
      } else {
#pragma unroll
        for (int r = 0; r < 4; ++r) {
          const int row = m0 + wm + mi * 16 + fq * 4 + r;
          float v = acc[mi][ni][r] + bias_v;
          if (DO_SELU) v = v > 0.0f ? 1.0507009873554805f * v
                                    : 1.7580993408473766f * (expf(v) - 1.0f);
          long addr = sCz * z + (long)row * N + col;
          if (F32OUT) ((float*)Cout)[addr] = v;
          else        ((bf16*)Cout)[addr] = (bf16)v;
        }
      }
    }
  }
}

// ---------------- launcher ----------------
extern "C" void kernel_launch(void* const* d_in, const int* in_sizes, int n_in,
                              void* d_out, int out_size, void* d_ws, size_t ws_size,
                              hipStream_t stream) {
  (void)in_sizes; (void)n_in; (void)out_size; (void)ws_size;
  const float* x_enc = (const float*)d_in[0];
  const float* x_dec = (const float*)d_in[1];
  const float* Wq = (const float*)d_in[2];
  const float* bq = (const float*)d_in[3];
  const float* Wk = (const float*)d_in[4];
  const float* bk = (const float*)d_in[5];
  const float* Wv = (const float*)d_in[6];
  const float* bv = (const float*)d_in[7];
  const float* Wo = (const float*)d_in[8];
  const float* bo = (const float*)d_in[9];
  const float* g1 = (const float*)d_in[10];
  const float* be1 = (const float*)d_in[11];
  const float* g2 = (const float*)d_in[12];
  const float* be2 = (const float*)d_in[13];
  const float* W1 = (const float*)d_in[14];
  const float* b1 = (const float*)d_in[15];
  const float* W2 = (const float*)d_in[16];
  const float* b2 = (const float*)d_in[17];
  const float* g3 = (const float*)d_in[18];
  const float* be3 = (const float*)d_in[19];

  char* ws = (char*)d_ws;
  const size_t MB = 1u << 20;
  // time-disjoint aliasing, peak 229 MiB
  bf16*  qlog   = (bf16*) (ws + 0);        // [0,32) Q logits -> dead after softmax
  bf16*  klog   = (bf16*) (ws + 32 * MB);  // [32,64) K logits -> dead after softmax
  bf16*  midb   = (bf16*) (ws + 32 * MB);  // W1 out
  bf16*  qs2    = (bf16*) (ws + 64 * MB);  // [64,96) softmax Q -> dead after attn GEMM
  float* ff_f   = (float*)(ws + 64 * MB);  // W2 out
  bf16*  ksT    = (bf16*) (ws + 96 * MB);  // [96,128) -> dead after gc GEMM
  float* attn_f = (float*)(ws + 96 * MB);  // attn GEMM out
  bf16*  vsT    = (bf16*) (ws + 128 * MB); // [128,160) -> dead after gc GEMM
  float* x2_f   = (float*)(ws + 128 * MB); // LN2 out (fp32)
  bf16*  x2_b   = (bf16*) (ws + 144 * MB); // [144,152) LN2 out (bf16)
  bf16*  gwT    = (bf16*) (ws + 152 * MB); // [152,160) gw out (Bt layout for attn GEMM)
  float* xd_f   = (float*)(ws + 160 * MB); // [160,176) LN1 out (fp32)
  bf16*  Yt     = (bf16*) (ws + 176 * MB); // [176,192) -> dead after fold
  float* xf_f   = (float*)(ws + 176 * MB); // Afold out -> dead after LN1
  bf16*  xdec_b = (bf16*) (ws + 192 * MB); // [192,200) dead after Yt GEMM
  bf16*  Yfold  = (bf16*) (ws + 192 * MB); // fold out -> dead after Afold GEMM
  bf16*  xd_b   = (bf16*) (ws + 192 * MB); // LN1 bf16 -> dead after Q GEMM
  bf16*  gc     = (bf16*) (ws + 192 * MB); // gc[z][d][e] -> dead after gw GEMM
  bf16*  xenc_b = (bf16*) (ws + 200 * MB); // [200,208) dead after K/V GEMMs
  bf16*  Ttrig  = (bf16*) (ws + 208 * MB);
  bf16*  Afold  = (bf16*) (ws + 209 * MB);
  bf16*  BtQ    = (bf16*) (ws + 217 * MB);
  bf16*  BtK    = (bf16*) (ws + 219 * MB);
  bf16*  WvT    = (bf16*) (ws + 221 * MB);
  bf16*  WoTh   = (bf16*) (ws + 223 * MB); // WoTh[h][n][e] = Wo[4e+h][n]
  bf16*  W1T    = (bf16*) (ws + 225 * MB);
  bf16*  W2T    = (bf16*) (ws + 227 * MB); // end 229 MiB

  // --- prep (one launch) ---
  prep_all<<<57344, 256, 0, stream>>>(x_dec, x_enc, Ttrig, Afold, xdec_b, xenc_b,
                                      Wq, Wk, Wv, Wo, W1, W2,
                                      BtQ, BtK, WvT, WoTh, W1T, W2T);

  // --- Fourier mixing ---
  gemm_bt<128, 0, 0, 0, 0, 1><<<512, 256, 0, stream>>>(
      Ttrig, xdec_b, nullptr, Yt, 2048, 512, 0L, 1048576L, 0L, 2097152L, 16, 8, 64);
  fold_y<<<16384, 256, 0, stream>>>(Yt, Yfold);
  gemm_bt<64, 0, 0, 0, 1, 1><<<512, 256, 0, stream>>>(
      Afold, Yfold, nullptr, xf_f, 512, 2048, 0L, 1048576L, 0L, 1048576L, 8, 16, 32);
  ln_kernel<1, 1><<<8192, 256, 0, stream>>>(x_dec, xf_f, g1, be1, xd_b, xd_f);

  // --- attention ---
  gemm_bt<128, 0, 2, 0, 0, 1><<<1024, 256, 0, stream>>>(   // Q logits [b,s,4e+h]
      xd_b, BtQ, bq, qlog, 2048, 512, 0L, 0L, 0L, 0L, 16, 64, 16);
  gemm_bt<128, 0, 2, 0, 0, 1><<<1024, 256, 0, stream>>>(   // K logits [b,s,4e+h]
      xenc_b, BtK, bk, klog, 2048, 512, 0L, 0L, 0L, 0L, 16, 64, 16);
  gemm_bt<128, 3, 1, 0, 0, 1><<<1024, 256, 0, stream>>>(   // V -> vsT[b,h,e,s]
      xenc_b, WvT, bv, vsT, 512, 512, 0L, 262144L, 512L, 0L, 4, 64, 16);
  softmax_qk<<<17408, 256, 0, stream>>>(qlog, qs2, klog, ksT);
  gemm_bt<64, 0, 0, 0, 0, 2><<<512, 256, 0, stream>>>(     // gc[z][d,e] (K=2048)
      ksT, vsT, nullptr, gc, 512, 2048, 1048576L, 1048576L, 0L, 262144L, 8, 4, 32);
  gemm_bt<64, 7, 0, 0, 0, 2, 1><<<512, 256, 0, stream>>>(  // gwT: WoTh[h] . gc[z]^T
      WoTh, gc, nullptr, gwT, 512, 512, 262144L, 262144L, 0L, 0L, 8, 4, 32);
  gemm_bt<64, 0, 1, 0, 1, 1><<<512, 256, 0, stream>>>(     // attn = qs2 . gwT^T + bo
      qs2, gwT, bo, attn_f, 512, 2048, 4194304L, 1048576L, 0L, 1048576L, 8, 16, 32);
  ln_kernel<1, 1><<<8192, 256, 0, stream>>>(xd_f, attn_f, g2, be2, x2_b, x2_f);

  // --- FFN ---
  gemm_bt<128, 0, 1, 1, 0, 1><<<1024, 256, 0, stream>>>(
      x2_b, W1T, b1, midb, 2048, 512, 0L, 0L, 0L, 0L, 16, 64, 16);
  gemm_bt<64, 0, 1, 0, 1, 1><<<512, 256, 0, stream>>>(
      midb, W2T, b2, ff_f, 512, 2048, 0L, 0L, 0L, 0L, 8, 64, 8);
  ln_kernel<0, 1><<<8192, 256, 0, stream>>>(x2_f, ff_f, g3, be3, nullptr, (float*)d_out);
}

// Round 7
// 436.051 us; speedup vs baseline: 1.1286x; 1.0808x over previous
//
#include <hip/hip_runtime.h>
#include <stdint.h>

typedef __bf16 bf16;
typedef __bf16 bf16x8 __attribute__((ext_vector_type(8)));
typedef float f32x4 __attribute__((ext_vector_type(4)));

// ---------------- async global->LDS (16B per lane) ----------------
static __device__ __forceinline__ void async16(const void* g, void* l) {
  __builtin_amdgcn_global_load_lds(
      (__attribute__((address_space(1))) void*)g,
      (__attribute__((address_space(3))) void*)l, 16, 0, 0);
}

// ---------------- merged prep: trig tables + casts + all weight transposes ----------------
// blocks [0,2048) ttrig | [2048,18432) afold | [18432,34816) cast x_dec |
// [34816,51200) cast x_enc | [51200,57344) weight transposes.
// Trig via native v_sin/v_cos (__sinf/__cosf): args are < 2*pi, accuracy >> bf16 eps.
__global__ void __launch_bounds__(256) prep_all(
    const float* __restrict__ xdec, const float* __restrict__ xenc,
    bf16* __restrict__ Ttrig, bf16* __restrict__ Afold,
    bf16* __restrict__ xdec_b, bf16* __restrict__ xenc_b,
    const float* __restrict__ Wq, const float* __restrict__ Wk,
    const float* __restrict__ Wv, const float* __restrict__ Wo,
    const float* __restrict__ W1, const float* __restrict__ W2,
    bf16* __restrict__ BtQ, bf16* __restrict__ BtK, bf16* __restrict__ WvT,
    bf16* __restrict__ WoTh, bf16* __restrict__ W1T, bf16* __restrict__ W2T) {
  __shared__ bf16 tile[32][33];
  int id = blockIdx.x;
  if (id < 2048) {                     // Ttrig[1024][512]
    int idx = id * 256 + threadIdx.x;
    int d = idx & 511, jp = idx >> 9;
    int jj = jp >> 1, p = jp & 1;
    int t = (d * jj) & 511;
    float ang = (float)t * (6.283185307179586f / 512.0f);
    Ttrig[idx] = (bf16)(p ? __sinf(ang) : __cosf(ang));
  } else if (id < 18432) {             // Afold[2048][2048]
    int idx = (id - 2048) * 256 + threadIdx.x;
    int k = idx & 2047, k1 = idx >> 11;
    int s = (k < 1025) ? k : (k - 1024);
    int t = (k1 * s) & 2047;
    float ang = (float)t * (6.283185307179586f / 2048.0f);
    Afold[idx] = (bf16)((k < 1025) ? __cosf(ang) : -__sinf(ang));
  } else if (id < 34816) {
    int i = (id - 18432) * 256 + threadIdx.x;
    xdec_b[i] = (bf16)xdec[i];
  } else if (id < 51200) {
    int i = (id - 34816) * 256 + threadIdx.x;
    xenc_b[i] = (bf16)xenc[i];
  } else {
    int id2 = id - 51200;
    int kind = id2 >> 10, t = id2 & 1023;
    const float* in; bf16* out; int R, C, rt, ct;
    bool iperm = false, hsel = false; int hh = 0;
    if (kind == 0)      { in = Wq; out = BtQ; R = 2048; C = 512; rt = t >> 4; ct = t & 15; iperm = true; }
    else if (kind == 1) { in = Wk; out = BtK; R = 2048; C = 512; rt = t >> 4; ct = t & 15; iperm = true; }
    else if (kind == 2) {
      int zz = t >> 8, tt = t & 255;
      in = Wv + (long)zz * 262144; out = WvT + (long)zz * 262144;
      R = 512; C = 512; rt = tt >> 4; ct = tt & 15;
    }
    else if (kind == 3) {              // WoTh[h][n][e] = Wo[4e+h][n]
      int zz = t >> 8, tt = t & 255;
      in = Wo; out = WoTh + (long)zz * 262144;
      R = 512; C = 512; rt = tt >> 4; ct = tt & 15; hsel = true; hh = zz;
    }
    else if (kind == 4) { in = W1; out = W1T; R = 512; C = 2048; rt = t >> 6; ct = t & 63; }
    else                { in = W2; out = W2T; R = 2048; C = 512; rt = t >> 4; ct = t & 15; }
    int c0 = ct * 32, r0 = rt * 32;
    int tx = threadIdx.x & 31, ty = threadIdx.x >> 5;
#pragma unroll
    for (int i = 0; i < 32; i += 8) {
      int r = r0 + ty + i;
      int rr = hsel ? (4 * r + hh) : r;
      tile[ty + i][tx] = (bf16)in[(long)rr * C + (c0 + tx)];
    }
    __syncthreads();
#pragma unroll
    for (int i = 0; i < 32; i += 8) {
      int cc = c0 + ty + i, rr = r0 + tx;
      if (iperm)   // Bt row n = 4e+h from Wq/Wk row h*512+din
        out[((long)(4 * cc + (rr >> 9)) << 9) + (rr & 511)] = tile[tx][ty + i];
      else
        out[(long)cc * R + rr] = tile[tx][ty + i];
    }
  }
}

// Fold Yt [4][512][4096] (k = p*2048+s) -> Yf [4][512][2048] via s <-> 2048-s symmetry.
__global__ void __launch_bounds__(256) fold_y(const bf16* __restrict__ Yt,
                                              bf16* __restrict__ Yf) {
  int idx = blockIdx.x * 256 + threadIdx.x;
  int k = idx & 2047;
  int j = (idx >> 11) & 511;
  int b = idx >> 20;
  const bf16* yin = Yt + (long)b * 2097152 + (long)j * 4096;
  float v;
  if (k < 1025) {
    if (k == 0) v = (float)yin[0];
    else if (k == 1024) v = (float)yin[1024];
    else v = (float)yin[k] + (float)yin[2048 - k];
  } else {
    int s = k - 1024;
    v = (float)yin[2048 + s] - (float)yin[2048 + 2048 - s];
  }
  Yf[(long)b * 1048576 + (long)j * 2048 + k] = (bf16)v;
}

// ---------------- head softmax pass ----------------
// blocks [0,16384): Q [b,s,4e+h] -> qs2[b,s,h*512+e] (in-row permute, coalesced)
// blocks [16384,17408): K -> ksT[b,h,d,s] via XOR-swizzled LDS 64x64 tile transpose
__global__ void __launch_bounds__(256) softmax_qk(
    const bf16* __restrict__ qlog, bf16* __restrict__ qs2,
    const bf16* __restrict__ klog, bf16* __restrict__ ksT) {
  __shared__ bf16 lds[4 * 64 * 64];   // [h][e][swizzled s]
  const int bid = blockIdx.x, t = threadIdx.x;
  if (bid < 16384) {
    int idx = bid * 256 + t;
    int e = idx & 511, s = (idx >> 9) & 2047, b = idx >> 20;
    bf16 raw[4] __attribute__((aligned(8)));
    *(uint2*)raw = *(const uint2*)(qlog + ((long)(b * 2048 + s) * 2048 + 4 * e));
    float v0 = (float)raw[0], v1 = (float)raw[1], v2 = (float)raw[2], v3 = (float)raw[3];
    float m = fmaxf(fmaxf(v0, v1), fmaxf(v2, v3));
    float e0 = __expf(v0 - m), e1 = __expf(v1 - m), e2 = __expf(v2 - m), e3 = __expf(v3 - m);
    float rs = 1.0f / (e0 + e1 + e2 + e3);
    long base = ((long)(b * 2048 + s)) * 2048 + e;   // h stride = 512 within row
    qs2[base] = (bf16)(e0 * rs);
    qs2[base + 512] = (bf16)(e1 * rs);
    qs2[base + 1024] = (bf16)(e2 * rs);
    qs2[base + 1536] = (bf16)(e3 * rs);
  } else {
    int tb = bid - 16384;            // 4b x 32 s-tiles x 8 e-tiles
    int b = tb >> 8, rem = tb & 255;
    int s0 = (rem >> 3) << 6, e0 = (rem & 7) << 6;
    int te = t & 63, tr = t >> 6;
#pragma unroll
    for (int i = 0; i < 16; ++i) {
      int s = tr + (i << 2);
      bf16 raw[4] __attribute__((aligned(8)));
      *(uint2*)raw = *(const uint2*)(klog + ((long)(b * 2048 + s0 + s) * 2048 + 4 * (e0 + te)));
      float v0 = (float)raw[0], v1 = (float)raw[1], v2 = (float)raw[2], v3 = (float)raw[3];
      float m = fmaxf(fmaxf(v0, v1), fmaxf(v2, v3));
      float x0 = __expf(v0 - m), x1 = __expf(v1 - m), x2 = __expf(v2 - m), x3 = __expf(v3 - m);
      float rs = 1.0f / (x0 + x1 + x2 + x3);
      int cp = ((((s >> 2) ^ (te & 15)) << 2) | (s & 3));
      int base = te * 64 + cp;
      lds[base] = (bf16)(x0 * rs);
      lds[4096 + base] = (bf16)(x1 * rs);
      lds[8192 + base] = (bf16)(x2 * rs);
      lds[12288 + base] = (bf16)(x3 * rs);
    }
    __syncthreads();
    int sc = t & 15, r = t >> 4;
#pragma unroll
    for (int i = 0; i < 16; ++i) {
      int he = r + (i << 4);         // 0..255
      int h = he >> 6, e = he & 63;
      int cp = (sc ^ (e & 15)) << 2;
      bf16 tmp[4] __attribute__((aligned(8)));
      *(uint2*)tmp = *(const uint2*)&lds[h * 4096 + e * 64 + cp];
      *(uint2*)(ksT + ((long)(b * 4 + h) * 512 + e0 + e) * 2048 + s0 + (sc << 2)) =
          *(const uint2*)tmp;
    }
  }
}

// ---------------- LayerNorm over D=512: out = g*((A+B) - mu)*rstd + be ----------------
template <typename TA, typename TB, int WRITE_BF16, int WRITE_F32>
__global__ void __launch_bounds__(256) ln_kernel(
    const TA* __restrict__ A, const TB* __restrict__ Bv,
    const float* __restrict__ g, const float* __restrict__ be,
    bf16* __restrict__ outb, float* __restrict__ outf) {
  const int row = blockIdx.x, t = threadIdx.x;
  const long base = (long)row * 512;
  float v0 = (float)A[base + t] + (float)Bv[base + t];
  float v1 = (float)A[base + t + 256] + (float)Bv[base + t + 256];
  float s = v0 + v1, q = v0 * v0 + v1 * v1;
#pragma unroll
  for (int off = 32; off > 0; off >>= 1) {
    s += __shfl_down(s, off);
    q += __shfl_down(q, off);
  }
  __shared__ float red[8];
  const int wv = t >> 6, ln = t & 63;
  if (ln == 0) { red[wv] = s; red[wv + 4] = q; }
  __syncthreads();
  float S = red[0] + red[1] + red[2] + red[3];
  float Q = red[4] + red[5] + red[6] + red[7];
  float mu = S * (1.0f / 512.0f);
  float var = Q * (1.0f / 512.0f) - mu * mu;
  float rstd = rsqrtf(var + 1e-5f);
  float o0 = g[t] * (v0 - mu) * rstd + be[t];
  float o1 = g[t + 256] * (v1 - mu) * rstd + be[t + 256];
  if (WRITE_BF16) { outb[base + t] = (bf16)o0; outb[base + t + 256] = (bf16)o1; }
  if (WRITE_F32)  { outf[base + t] = o0; outf[base + t + 256] = o1; }
}

// ---------------- GEMM: C = A[M,K] * Bt[N,K]^T (single-buffer m97 K-loop) --------------
// SWIZ: 0 plain; 1 group-by-y (flat%8==y%8); 2 group-by-z. gin = blocks per group.
// ADDR_MODE: 0 plain (sCz*z); 7 gw out (z=b*4+h -> Bt_b[n=row][h*512+col]).
// HAS_BIAS: 0 none, 1 bias[sBiasz*z+col].  AHEAD: A += sAz*(z&3).
template <int BN, int ADDR_MODE, int HAS_BIAS, int DO_SELU, int F32OUT, int SWIZ,
          int AHEAD = 0>
__global__ void __launch_bounds__(256, 2) gemm_bt(
    const bf16* __restrict__ A, const bf16* __restrict__ Bt,
    const float* __restrict__ bias, void* __restrict__ Cout,
    int N, int K, long sAz, long sBz, long sBiasz, long sCz,
    int gx, int gy, int gin) {
  __shared__ __align__(16) bf16 lA[128 * 64];
  __shared__ __align__(16) bf16 lB[BN * 64];
  int x, y, z;
  {
    int id = blockIdx.x;
    if (SWIZ == 0) {
      x = id % gx; int t2 = id / gx; y = t2 % gy; z = t2 / gy;
    } else {
      int xcd = id & 7, r = id >> 3;
      int inner = r % gin, G = xcd + 8 * (r / gin);
      if (SWIZ == 1) { y = G; x = inner % gx; z = inner / gx; }
      else           { z = G; x = inner % gx; y = inner / gx; }
    }
  }
  A  += AHEAD ? sAz * (z & 3) : sAz * z;
  Bt += sBz * z;
  const int m0 = y * 128, n0 = x * BN;
  const int t = threadIdx.x;
  const int lane = t & 63, wave = t >> 6;
  const int srow = t >> 3;
  const int pch  = t & 7;
  const int lch  = pch ^ (srow & 7);   // XOR bank swizzle (global-side)
  const bf16* Ag = A  + (long)(m0 + srow) * K + lch * 8;
  const bf16* Bg = Bt + (long)(n0 + srow) * K + lch * 8;
  bf16* lAp = lA + srow * 64 + pch * 8;
  bf16* lBp = lB + srow * 64 + pch * 8;
  constexpr int MI = (BN == 128) ? 4 : 2;
  const int wm = (BN == 128) ? (wave >> 1) * 64 : wave * 32;
  const int wn = (BN == 128) ? (wave & 1) * 64 : 0;
  const int fr = lane & 15, fq = lane >> 4;

  f32x4 acc[MI][4] = {};

  for (int k0 = 0; k0 < K; k0 += 64) {
    __syncthreads();
#pragma unroll
    for (int i = 0; i < 4; ++i)
      async16(Ag + k0 + (long)(32 * i) * K, lAp + 32 * i * 64);
#pragma unroll
    for (int i = 0; i < BN / 32; ++i)
      async16(Bg + k0 + (long)(32 * i) * K, lBp + 32 * i * 64);
    __syncthreads();
#pragma unroll
    for (int kk = 0; kk < 2; ++kk) {
      bf16x8 av[MI], bfrag[4];
#pragma unroll
      for (int mi = 0; mi < MI; ++mi) {
        int r = wm + mi * 16 + fr;
        int c = (kk * 4 + fq) ^ (r & 7);
        av[mi] = *(const bf16x8*)&lA[r * 64 + c * 8];
      }
#pragma unroll
      for (int ni = 0; ni < 4; ++ni) {
        int r = wn + ni * 16 + fr;
        int c = (kk * 4 + fq) ^ (r & 7);
        bfrag[ni] = *(const bf16x8*)&lB[r * 64 + c * 8];
      }
#pragma unroll
      for (int mi = 0; mi < MI; ++mi)
#pragma unroll
        for (int ni = 0; ni < 4; ++ni)
          acc[mi][ni] = __builtin_amdgcn_mfma_f32_16x16x32_bf16(
              av[mi], bfrag[ni], acc[mi][ni], 0, 0, 0);
    }
  }

  // epilogue: C/D layout col = lane&15, row = (lane>>4)*4 + reg
#pragma unroll
  for (int mi = 0; mi < MI; ++mi) {
#pragma unroll
    for (int ni = 0; ni < 4; ++ni) {
      const int col = n0 + wn + ni * 16 + fr;
      float bias_v = 0.0f;
      if (HAS_BIAS == 1) bias_v = bias[sBiasz * z + col];
      if (ADDR_MODE == 7) {                  // z=b*4+h -> Bt_b[n=row][h*512+col]
        const int b = z >> 2, h = z & 3;
#pragma unroll
        for (int r = 0; r < 4; ++r) {
          const int row = m0 + wm + mi * 16 + fq * 4 + r;
          ((bf16*)Cout)[((long)(b * 512 + row)) * 2048 + h * 512 + col] =
              (bf16)(acc[mi][ni][r] + bias_v);
        }
      } else {
#pragma unroll
        for (int r = 0; r < 4; ++r) {
          const int row = m0 + wm + mi * 16 + fq * 4 + r;
          float v = acc[mi][ni][r] + bias_v;
          if (DO_SELU) v = v > 0.0f ? 1.0507009873554805f * v
                                    : 1.7580993408473766f * (__expf(v) - 1.0f);
          long addr = sCz * z + (long)row * N + col;
          if (F32OUT) ((float*)Cout)[addr] = v;
          else        ((bf16*)Cout)[addr] = (bf16)v;
        }
      }
    }
  }
}

// ---------------- merged Q/K/V projection GEMM (3072 blocks, K=512, BM=BN=128) ----------
// seg 0: Q = xd.BtQ + bq -> qlog[b,s,4e+h]; seg 1: K = xenc.BtK + bk -> klog;
// seg 2: V = xenc.WvT[h] + bv -> vsT[b,h,e,s] (8B packed transposed store).
__global__ void __launch_bounds__(256, 2) gemm_qkv(
    const bf16* __restrict__ Aq, const bf16* __restrict__ Aenc,
    const bf16* __restrict__ BQ, const bf16* __restrict__ BK,
    const bf16* __restrict__ BV,
    const float* __restrict__ bq, const float* __restrict__ bk,
    const float* __restrict__ bv,
    bf16* __restrict__ qlog, bf16* __restrict__ klog, bf16* __restrict__ vsT) {
  __shared__ __align__(16) bf16 lA[128 * 64];
  __shared__ __align__(16) bf16 lB[128 * 64];
  const int id = blockIdx.x;
  const int seg = id >> 10, sid = id & 1023;
  const int xcd = sid & 7, r = sid >> 3;
  const int inner = r & 15, y = xcd + 8 * (r >> 4);   // y in 0..63
  int x, z;
  const bf16 *A, *Bt; bf16* out; const float* bias;
  if (seg == 0)      { x = inner; z = 0; A = Aq;   Bt = BQ; out = qlog; bias = bq; }
  else if (seg == 1) { x = inner; z = 0; A = Aenc; Bt = BK; out = klog; bias = bk; }
  else { x = inner & 3; z = inner >> 2; A = Aenc; Bt = BV + (long)z * 262144;
         out = vsT; bias = bv + z * 512; }
  const int K = 512;
  const int m0 = y * 128, n0 = x * 128;
  const int t = threadIdx.x;
  const int lane = t & 63, wave = t >> 6;
  const int srow = t >> 3, pch = t & 7, lch = pch ^ (srow & 7);
  const bf16* Ag = A  + (long)(m0 + srow) * K + lch * 8;
  const bf16* Bg = Bt + (long)(n0 + srow) * K + lch * 8;
  bf16* lAp = lA + srow * 64 + pch * 8;
  bf16* lBp = lB + srow * 64 + pch * 8;
  const int wm = (wave >> 1) * 64, wn = (wave & 1) * 64;
  const int fr = lane & 15, fq = lane >> 4;

  f32x4 acc[4][4] = {};
  for (int k0 = 0; k0 < K; k0 += 64) {
    __syncthreads();
#pragma unroll
    for (int i = 0; i < 4; ++i) {
      async16(Ag + k0 + (long)(32 * i) * K, lAp + 32 * i * 64);
      async16(Bg + k0 + (long)(32 * i) * K, lBp + 32 * i * 64);
    }
    __syncthreads();
#pragma unroll
    for (int kk = 0; kk < 2; ++kk) {
      bf16x8 av[4], bfrag[4];
#pragma unroll
      for (int mi = 0; mi < 4; ++mi) {
        int rr = wm + mi * 16 + fr;
        int c = (kk * 4 + fq) ^ (rr & 7);
        av[mi] = *(const bf16x8*)&lA[rr * 64 + c * 8];
      }
#pragma unroll
      for (int ni = 0; ni < 4; ++ni) {
        int rr = wn + ni * 16 + fr;
        int c = (kk * 4 + fq) ^ (rr & 7);
        bfrag[ni] = *(const bf16x8*)&lB[rr * 64 + c * 8];
      }
#pragma unroll
      for (int mi = 0; mi < 4; ++mi)
#pragma unroll
        for (int ni = 0; ni < 4; ++ni)
          acc[mi][ni] = __builtin_amdgcn_mfma_f32_16x16x32_bf16(
              av[mi], bfrag[ni], acc[mi][ni], 0, 0, 0);
    }
  }

#pragma unroll
  for (int mi = 0; mi < 4; ++mi) {
#pragma unroll
    for (int ni = 0; ni < 4; ++ni) {
      const int col = n0 + wn + ni * 16 + fr;
      if (seg < 2) {
        const float bias_v = bias[(col & 3) * 512 + (col >> 2)];
#pragma unroll
        for (int r = 0; r < 4; ++r) {
          const int row = m0 + wm + mi * 16 + fq * 4 + r;
          out[(long)row * 2048 + col] = (bf16)(acc[mi][ni][r] + bias_v);
        }
      } else {
        const float bias_v = bias[col];
        const int row0 = m0 + wm + mi * 16 + fq * 4;
        const int b = row0 >> 11, s = row0 & 2047;
        bf16 tmp[4] __attribute__((aligned(8)));
#pragma unroll
        for (int r = 0; r < 4; ++r) tmp[r] = (bf16)(acc[mi][ni][r] + bias_v);
        long addr = ((long)((b << 2) + z) * 512 + col) * 2048 + s;
        *(uint2*)(out + addr) = *(const uint2*)tmp;
      }
    }
  }
}

// ---------------- launcher ----------------
extern "C" void kernel_launch(void* const* d_in, const int* in_sizes, int n_in,
                              void* d_out, int out_size, void* d_ws, size_t ws_size,
                              hipStream_t stream) {
  (void)in_sizes; (void)n_in; (void)out_size; (void)ws_size;
  const float* x_enc = (const float*)d_in[0];
  const float* x_dec = (const float*)d_in[1];
  const float* Wq = (const float*)d_in[2];
  const float* bq = (const float*)d_in[3];
  const float* Wk = (const float*)d_in[4];
  const float* bk = (const float*)d_in[5];
  const float* Wv = (const float*)d_in[6];
  const float* bv = (const float*)d_in[7];
  const float* Wo = (const float*)d_in[8];
  const float* bo = (const float*)d_in[9];
  const float* g1 = (const float*)d_in[10];
  const float* be1 = (const float*)d_in[11];
  const float* g2 = (const float*)d_in[12];
  const float* be2 = (const float*)d_in[13];
  const float* W1 = (const float*)d_in[14];
  const float* b1 = (const float*)d_in[15];
  const float* W2 = (const float*)d_in[16];
  const float* b2 = (const float*)d_in[17];
  const float* g3 = (const float*)d_in[18];
  const float* be3 = (const float*)d_in[19];

  char* ws = (char*)d_ws;
  const size_t MB = 1u << 20;
  // time-disjoint aliasing, peak 229 MiB
  bf16*  qlog   = (bf16*) (ws + 0);        // [0,32)   dead after softmax
  bf16*  klog   = (bf16*) (ws + 32 * MB);  // [32,64)  dead after softmax
  bf16*  midb   = (bf16*) (ws + 32 * MB);  // W1 out
  bf16*  qs2    = (bf16*) (ws + 64 * MB);  // [64,96)  dead after attn GEMM
  bf16*  ff_b   = (bf16*) (ws + 64 * MB);  // W2 out (bf16)
  bf16*  ksT    = (bf16*) (ws + 96 * MB);  // [96,128) dead after gc GEMM
  bf16*  attn_b = (bf16*) (ws + 96 * MB);  // attn GEMM out (bf16)
  bf16*  vsT    = (bf16*) (ws + 128 * MB); // [128,160) dead after gc GEMM
  bf16*  x2_b   = (bf16*) (ws + 128 * MB); // LN2 out (after gc)
  bf16*  gwT    = (bf16*) (ws + 152 * MB); // [152,160) gw out (after gc)
  bf16*  xd_b   = (bf16*) (ws + 160 * MB); // [160,168) LN1 out, lives to LN2
  bf16*  Yt     = (bf16*) (ws + 176 * MB); // [176,192) dead after fold
  bf16*  xf_b   = (bf16*) (ws + 176 * MB); // Afold out (bf16, after Yt dead)
  bf16*  xdec_b = (bf16*) (ws + 192 * MB); // [192,200) dead after Yt GEMM
  bf16*  Yfold  = (bf16*) (ws + 192 * MB); // fold out, dead after Afold GEMM
  bf16*  gc     = (bf16*) (ws + 192 * MB); // gc GEMM out (after Afold)
  bf16*  xenc_b = (bf16*) (ws + 200 * MB); // [200,208) dead after QKV GEMM
  bf16*  Ttrig  = (bf16*) (ws + 208 * MB);
  bf16*  Afold  = (bf16*) (ws + 209 * MB);
  bf16*  BtQ    = (bf16*) (ws + 217 * MB);
  bf16*  BtK    = (bf16*) (ws + 219 * MB);
  bf16*  WvT    = (bf16*) (ws + 221 * MB);
  bf16*  WoTh   = (bf16*) (ws + 223 * MB); // WoTh[h][n][e] = Wo[4e+h][n]
  bf16*  W1T    = (bf16*) (ws + 225 * MB);
  bf16*  W2T    = (bf16*) (ws + 227 * MB); // end 229 MiB

  // --- prep (one launch) ---
  prep_all<<<57344, 256, 0, stream>>>(x_dec, x_enc, Ttrig, Afold, xdec_b, xenc_b,
                                      Wq, Wk, Wv, Wo, W1, W2,
                                      BtQ, BtK, WvT, WoTh, W1T, W2T);

  // --- Fourier mixing ---
  gemm_bt<128, 0, 0, 0, 0, 1><<<512, 256, 0, stream>>>(
      Ttrig, xdec_b, nullptr, Yt, 2048, 512, 0L, 1048576L, 0L, 2097152L, 16, 8, 64);
  fold_y<<<16384, 256, 0, stream>>>(Yt, Yfold);
  gemm_bt<64, 0, 0, 0, 0, 1><<<512, 256, 0, stream>>>(   // xf (bf16 out)
      Afold, Yfold, nullptr, xf_b, 512, 2048, 0L, 1048576L, 0L, 1048576L, 8, 16, 32);
  ln_kernel<float, bf16, 1, 0><<<8192, 256, 0, stream>>>(
      x_dec, xf_b, g1, be1, xd_b, nullptr);

  // --- attention ---
  gemm_qkv<<<3072, 256, 0, stream>>>(xd_b, xenc_b, BtQ, BtK, WvT,
                                     bq, bk, bv, qlog, klog, vsT);
  softmax_qk<<<17408, 256, 0, stream>>>(qlog, qs2, klog, ksT);
  gemm_bt<64, 0, 0, 0, 0, 2><<<512, 256, 0, stream>>>(     // gc[z][d,e] (K=2048)
      ksT, vsT, nullptr, gc, 512, 2048, 1048576L, 1048576L, 0L, 262144L, 8, 4, 32);
  gemm_bt<64, 7, 0, 0, 0, 2, 1><<<512, 256, 0, stream>>>(  // gwT: WoTh[h] . gc[z]^T
      WoTh, gc, nullptr, gwT, 512, 512, 262144L, 262144L, 0L, 0L, 8, 4, 32);
  gemm_bt<64, 0, 1, 0, 0, 1><<<512, 256, 0, stream>>>(     // attn = qs2 . gwT^T + bo
      qs2, gwT, bo, attn_b, 512, 2048, 4194304L, 1048576L, 0L, 1048576L, 8, 16, 32);
  ln_kernel<bf16, bf16, 1, 0><<<8192, 256, 0, stream>>>(
      xd_b, attn_b, g2, be2, x2_b, nullptr);

  // --- FFN ---
  gemm_bt<128, 0, 1, 1, 0, 1><<<1024, 256, 0, stream>>>(
      x2_b, W1T, b1, midb, 2048, 512, 0L, 0L, 0L, 0L, 16, 64, 16);
  gemm_bt<64, 0, 1, 0, 0, 1><<<512, 256, 0, stream>>>(
      midb, W2T, b2, ff_b, 512, 2048, 0L, 0L, 0L, 0L, 8, 64, 8);
  ln_kernel<bf16, bf16, 0, 1><<<8192, 256, 0, stream>>>(
      x2_b, ff_b, g3, be3, nullptr, (float*)d_out);
}

// Round 8
// 413.497 us; speedup vs baseline: 1.1901x; 1.0545x over previous
//
#include <hip/hip_runtime.h>
#include <stdint.h>

typedef __bf16 bf16;
typedef __bf16 bf16x8 __attribute__((ext_vector_type(8)));
typedef float f32x4 __attribute__((ext_vector_type(4)));

// ---------------- async global->LDS (16B per lane) ----------------
static __device__ __forceinline__ void async16(const void* g, void* l) {
  __builtin_amdgcn_global_load_lds(
      (__attribute__((address_space(1))) void*)g,
      (__attribute__((address_space(3))) void*)l, 16, 0, 0);
}

// ---------------- merged prep ----------------
// blocks [0,2048) Ttrig | [2048,11840) Atrig2 (cos|sin half-DFT, K=1088) |
// [11840,28224) cast x_dec | [28224,44608) cast x_enc | [44608,50752) weight transposes
__global__ void __launch_bounds__(256) prep_all(
    const float* __restrict__ xdec, const float* __restrict__ xenc,
    bf16* __restrict__ Ttrig, bf16* __restrict__ Atrig2,
    bf16* __restrict__ xdec_b, bf16* __restrict__ xenc_b,
    const float* __restrict__ Wq, const float* __restrict__ Wk,
    const float* __restrict__ Wv, const float* __restrict__ Wo,
    const float* __restrict__ W1, const float* __restrict__ W2,
    bf16* __restrict__ BtQ, bf16* __restrict__ BtK, bf16* __restrict__ BtV,
    bf16* __restrict__ WoTh, bf16* __restrict__ W1T, bf16* __restrict__ W2T) {
  __shared__ bf16 tile[32][33];
  int id = blockIdx.x;
  if (id < 2048) {                     // Ttrig[1024][512]
    int idx = id * 256 + threadIdx.x;
    int d = idx & 511, jp = idx >> 9;
    int jj = jp >> 1, p = jp & 1;
    int t = (d * jj) & 511;
    float ang = (float)t * (6.283185307179586f / 512.0f);
    Ttrig[idx] = (bf16)(p ? __sinf(ang) : __cosf(ang));
  } else if (id < 11840) {             // Atrig2[2][1152][1088]: half 0 cos, half 1 -sin
    int idx = (id - 2048) * 256 + threadIdx.x;   // < 2506752
    int k = idx % 1088;
    int rr = idx / 1088;
    int r = rr % 1152, half = rr / 1152;
    float v = 0.0f;
    int tt = (r * k) & 2047;
    float ang = (float)tt * (6.283185307179586f / 2048.0f);
    if (half == 0) { if (r <= 1024 && k <= 1024) v = __cosf(ang); }
    else           { if (r <= 1023 && k >= 1 && k <= 1023) v = -__sinf(ang); }
    Atrig2[idx] = (bf16)v;
  } else if (id < 28224) {
    int i = (id - 11840) * 256 + threadIdx.x;
    xdec_b[i] = (bf16)xdec[i];
  } else if (id < 44608) {
    int i = (id - 28224) * 256 + threadIdx.x;
    xenc_b[i] = (bf16)xenc[i];
  } else {
    int id2 = id - 44608;
    int kind = id2 >> 10, t = id2 & 1023;
    const float* in; bf16* out; int R, C, rt, ct;
    bool iperm = false, hsel = false; int hh = 0;
    if (kind == 0)      { in = Wq; out = BtQ; R = 2048; C = 512; rt = t >> 4; ct = t & 15; iperm = true; }
    else if (kind == 1) { in = Wk; out = BtK; R = 2048; C = 512; rt = t >> 4; ct = t & 15; iperm = true; }
    else if (kind == 2) { in = Wv; out = BtV; R = 2048; C = 512; rt = t >> 4; ct = t & 15; iperm = true; }
    else if (kind == 3) {              // WoTh[h][n][e] = Wo[4e+h][n]
      int zz = t >> 8, tt = t & 255;
      in = Wo; out = WoTh + (long)zz * 262144;
      R = 512; C = 512; rt = tt >> 4; ct = tt & 15; hsel = true; hh = zz;
    }
    else if (kind == 4) { in = W1; out = W1T; R = 512; C = 2048; rt = t >> 6; ct = t & 63; }
    else                { in = W2; out = W2T; R = 2048; C = 512; rt = t >> 4; ct = t & 15; }
    int c0 = ct * 32, r0 = rt * 32;
    int tx = threadIdx.x & 31, ty = threadIdx.x >> 5;
#pragma unroll
    for (int i = 0; i < 32; i += 8) {
      int r = r0 + ty + i;
      int rr = hsel ? (4 * r + hh) : r;
      tile[ty + i][tx] = (bf16)in[(long)rr * C + (c0 + tx)];
    }
    __syncthreads();
#pragma unroll
    for (int i = 0; i < 32; i += 8) {
      int cc = c0 + ty + i, rr = r0 + tx;
      if (iperm)   // Bt row n = 4e+h from W row h*512+din
        out[((long)(4 * cc + (rr >> 9)) << 9) + (rr & 511)] = tile[tx][ty + i];
      else
        out[(long)cc * R + rr] = tile[tx][ty + i];
    }
  }
}

// Fold Yt [4][512][4096] -> Yf2 [8][512][1088]: z<4 cos-fold Ycf[b], z>=4 sin-fold Ysf[b]
__global__ void __launch_bounds__(256) fold_y(const bf16* __restrict__ Yt,
                                              bf16* __restrict__ Yf2) {
  int idx = blockIdx.x * 256 + threadIdx.x;   // 8*512*1088 = 4456448
  int k = idx % 1088;
  int rr = idx / 1088;
  int j = rr & 511, z = rr >> 9;
  int b = z & 3, half = z >> 2;
  const bf16* yin = Yt + (long)b * 2097152 + (long)j * 4096;
  float v = 0.0f;
  if (half == 0) {
    if (k == 0) v = (float)yin[0];
    else if (k == 1024) v = (float)yin[1024];
    else if (k < 1024) v = (float)yin[k] + (float)yin[2048 - k];
  } else {
    if (k >= 1 && k <= 1023) v = (float)yin[2048 + k] - (float)yin[4096 - k];
  }
  Yf2[(long)z * 557056 + (long)j * 1088 + k] = (bf16)v;
}

// ---------------- LN1 with DFT recombination: xf[s] = C[s'] ± S[s'] ----------------
__global__ void __launch_bounds__(256) ln1_kernel(
    const float* __restrict__ xdec, const bf16* __restrict__ CSb,
    const float* __restrict__ g, const float* __restrict__ be,
    bf16* __restrict__ outb) {
  const int row = blockIdx.x, t = threadIdx.x;
  const int b = row >> 11, s = row & 2047;
  const int sp = (s <= 1024) ? s : 2048 - s;
  const float sgn = (s <= 1024) ? 1.0f : -1.0f;
  const bf16* Crow = CSb + ((long)b * 1152 + sp) * 512;
  const bf16* Srow = CSb + ((long)(b + 4) * 1152 + sp) * 512;
  const long base = (long)row * 512;
  float v0 = xdec[base + t] + (float)Crow[t] + sgn * (float)Srow[t];
  float v1 = xdec[base + t + 256] + (float)Crow[t + 256] + sgn * (float)Srow[t + 256];
  float sm = v0 + v1, q = v0 * v0 + v1 * v1;
#pragma unroll
  for (int off = 32; off > 0; off >>= 1) {
    sm += __shfl_down(sm, off);
    q += __shfl_down(q, off);
  }
  __shared__ float red[8];
  const int wv = t >> 6, ln = t & 63;
  if (ln == 0) { red[wv] = sm; red[wv + 4] = q; }
  __syncthreads();
  float S = red[0] + red[1] + red[2] + red[3];
  float Q = red[4] + red[5] + red[6] + red[7];
  float mu = S * (1.0f / 512.0f);
  float var = Q * (1.0f / 512.0f) - mu * mu;
  float rstd = rsqrtf(var + 1e-5f);
  outb[base + t] = (bf16)(g[t] * (v0 - mu) * rstd + be[t]);
  outb[base + t + 256] = (bf16)(g[t + 256] * (v1 - mu) * rstd + be[t + 256]);
}

// ---------------- softmax / transpose pass ----------------
// [0,16384): Q [b,s,4e+h] -> qs2[b,s,h*512+e] (softmax, coalesced)
// [16384,17408): K -> ksT[b,h,d,s] (softmax + LDS transpose)
// [17408,18432): V -> vsT[b,h,e,s] (LDS transpose only)
__global__ void __launch_bounds__(256) softmax_qkv(
    const bf16* __restrict__ qlog, bf16* __restrict__ qs2,
    const bf16* __restrict__ klog, bf16* __restrict__ ksT,
    const bf16* __restrict__ vlog, bf16* __restrict__ vsT) {
  __shared__ bf16 lds[4 * 64 * 64];
  const int bid = blockIdx.x, t = threadIdx.x;
  if (bid < 16384) {
    int idx = bid * 256 + t;
    int e = idx & 511, s = (idx >> 9) & 2047, b = idx >> 20;
    bf16 raw[4] __attribute__((aligned(8)));
    *(uint2*)raw = *(const uint2*)(qlog + ((long)(b * 2048 + s) * 2048 + 4 * e));
    float v0 = (float)raw[0], v1 = (float)raw[1], v2 = (float)raw[2], v3 = (float)raw[3];
    float m = fmaxf(fmaxf(v0, v1), fmaxf(v2, v3));
    float e0 = __expf(v0 - m), e1 = __expf(v1 - m), e2 = __expf(v2 - m), e3 = __expf(v3 - m);
    float rs = 1.0f / (e0 + e1 + e2 + e3);
    long base = ((long)(b * 2048 + s)) * 2048 + e;
    qs2[base] = (bf16)(e0 * rs);
    qs2[base + 512] = (bf16)(e1 * rs);
    qs2[base + 1024] = (bf16)(e2 * rs);
    qs2[base + 1536] = (bf16)(e3 * rs);
  } else {
    const bool isK = bid < 17408;
    int tb = bid - (isK ? 16384 : 17408);  // 4b x 32 s-tiles x 8 e-tiles
    const bf16* src = isK ? klog : vlog;
    bf16* dst = isK ? ksT : vsT;
    int b = tb >> 8, rem = tb & 255;
    int s0 = (rem >> 3) << 6, e0 = (rem & 7) << 6;
    int te = t & 63, tr = t >> 6;
#pragma unroll
    for (int i = 0; i < 16; ++i) {
      int s = tr + (i << 2);
      bf16 raw[4] __attribute__((aligned(8)));
      *(uint2*)raw = *(const uint2*)(src + ((long)(b * 2048 + s0 + s) * 2048 + 4 * (e0 + te)));
      float x0 = (float)raw[0], x1 = (float)raw[1], x2 = (float)raw[2], x3 = (float)raw[3];
      if (isK) {
        float m = fmaxf(fmaxf(x0, x1), fmaxf(x2, x3));
        float y0 = __expf(x0 - m), y1 = __expf(x1 - m), y2 = __expf(x2 - m), y3 = __expf(x3 - m);
        float rs = 1.0f / (y0 + y1 + y2 + y3);
        x0 = y0 * rs; x1 = y1 * rs; x2 = y2 * rs; x3 = y3 * rs;
      }
      int cp = ((((s >> 2) ^ (te & 15)) << 2) | (s & 3));
      int base = te * 64 + cp;
      lds[base] = (bf16)x0;
      lds[4096 + base] = (bf16)x1;
      lds[8192 + base] = (bf16)x2;
      lds[12288 + base] = (bf16)x3;
    }
    __syncthreads();
    int sc = t & 15, r = t >> 4;
#pragma unroll
    for (int i = 0; i < 16; ++i) {
      int he = r + (i << 4);
      int h = he >> 6, e = he & 63;
      int cp = (sc ^ (e & 15)) << 2;
      bf16 tmp[4] __attribute__((aligned(8)));
      *(uint2*)tmp = *(const uint2*)&lds[h * 4096 + e * 64 + cp];
      *(uint2*)(dst + ((long)(b * 4 + h) * 512 + e0 + e) * 2048 + s0 + (sc << 2)) =
          *(const uint2*)tmp;
    }
  }
}

// ---------------- generic LayerNorm ----------------
template <typename TA, typename TB, int WRITE_BF16, int WRITE_F32>
__global__ void __launch_bounds__(256) ln_kernel(
    const TA* __restrict__ A, const TB* __restrict__ Bv,
    const float* __restrict__ g, const float* __restrict__ be,
    bf16* __restrict__ outb, float* __restrict__ outf) {
  const int row = blockIdx.x, t = threadIdx.x;
  const long base = (long)row * 512;
  float v0 = (float)A[base + t] + (float)Bv[base + t];
  float v1 = (float)A[base + t + 256] + (float)Bv[base + t + 256];
  float s = v0 + v1, q = v0 * v0 + v1 * v1;
#pragma unroll
  for (int off = 32; off > 0; off >>= 1) {
    s += __shfl_down(s, off);
    q += __shfl_down(q, off);
  }
  __shared__ float red[8];
  const int wv = t >> 6, ln = t & 63;
  if (ln == 0) { red[wv] = s; red[wv + 4] = q; }
  __syncthreads();
  float S = red[0] + red[1] + red[2] + red[3];
  float Q = red[4] + red[5] + red[6] + red[7];
  float mu = S * (1.0f / 512.0f);
  float var = Q * (1.0f / 512.0f) - mu * mu;
  float rstd = rsqrtf(var + 1e-5f);
  float o0 = g[t] * (v0 - mu) * rstd + be[t];
  float o1 = g[t + 256] * (v1 - mu) * rstd + be[t + 256];
  if (WRITE_BF16) { outb[base + t] = (bf16)o0; outb[base + t + 256] = (bf16)o1; }
  if (WRITE_F32)  { outf[base + t] = o0; outf[base + t + 256] = o1; }
}

// ---------------- GEMM: C = A[M,K] * Bt[N,K]^T (single-buffer m97 K-loop) --------------
// SWIZ: 0 plain; 1 group-by-y; 2 group-by-z; 3 group-by-x. gin = blocks per group.
// ADDR_MODE: 0 plain (sCz*z); 7 gw out (z=b*4+h -> Bt_b[n=row][h*512+col]).
// HAS_BIAS: 0 none, 1 bias[sBiasz*z+col].
// AHEAD: 0 A+=sAz*z; 1 A+=sAz*(z&3); 2 A+=sAz*(z>>2).
template <int BN, int ADDR_MODE, int HAS_BIAS, int DO_SELU, int F32OUT, int SWIZ,
          int AHEAD = 0>
__global__ void __launch_bounds__(256, 2) gemm_bt(
    const bf16* __restrict__ A, const bf16* __restrict__ Bt,
    const float* __restrict__ bias, void* __restrict__ Cout,
    int N, int K, long sAz, long sBz, long sBiasz, long sCz,
    int gx, int gy, int gin) {
  __shared__ __align__(16) bf16 lA[128 * 64];
  __shared__ __align__(16) bf16 lB[BN * 64];
  int x, y, z;
  {
    int id = blockIdx.x;
    if (SWIZ == 0) {
      x = id % gx; int t2 = id / gx; y = t2 % gy; z = t2 / gy;
    } else {
      int xcd = id & 7, r = id >> 3;
      int inner = r % gin, G = xcd + 8 * (r / gin);
      if (SWIZ == 1)      { y = G; x = inner % gx; z = inner / gx; }
      else if (SWIZ == 2) { z = G; x = inner % gx; y = inner / gx; }
      else                { x = G; y = inner % gy; z = inner / gy; }
    }
  }
  A  += (AHEAD == 1) ? sAz * (z & 3) : (AHEAD == 2) ? sAz * (z >> 2) : sAz * z;
  Bt += sBz * z;
  const int m0 = y * 128, n0 = x * BN;
  const int t = threadIdx.x;
  const int lane = t & 63, wave = t >> 6;
  const int srow = t >> 3;
  const int pch  = t & 7;
  const int lch  = pch ^ (srow & 7);   // XOR bank swizzle (global-side)
  const bf16* Ag = A  + (long)(m0 + srow) * K + lch * 8;
  const bf16* Bg = Bt + (long)(n0 + srow) * K + lch * 8;
  bf16* lAp = lA + srow * 64 + pch * 8;
  bf16* lBp = lB + srow * 64 + pch * 8;
  constexpr int MI = (BN == 128) ? 4 : 2;
  const int wm = (BN == 128) ? (wave >> 1) * 64 : wave * 32;
  const int wn = (BN == 128) ? (wave & 1) * 64 : 0;
  const int fr = lane & 15, fq = lane >> 4;

  f32x4 acc[MI][4] = {};

  for (int k0 = 0; k0 < K; k0 += 64) {
    __syncthreads();
#pragma unroll
    for (int i = 0; i < 4; ++i)
      async16(Ag + k0 + (long)(32 * i) * K, lAp + 32 * i * 64);
#pragma unroll
    for (int i = 0; i < BN / 32; ++i)
      async16(Bg + k0 + (long)(32 * i) * K, lBp + 32 * i * 64);
    __syncthreads();
#pragma unroll
    for (int kk = 0; kk < 2; ++kk) {
      bf16x8 av[MI], bfrag[4];
#pragma unroll
      for (int mi = 0; mi < MI; ++mi) {
        int r = wm + mi * 16 + fr;
        int c = (kk * 4 + fq) ^ (r & 7);
        av[mi] = *(const bf16x8*)&lA[r * 64 + c * 8];
      }
#pragma unroll
      for (int ni = 0; ni < 4; ++ni) {
        int r = wn + ni * 16 + fr;
        int c = (kk * 4 + fq) ^ (r & 7);
        bfrag[ni] = *(const bf16x8*)&lB[r * 64 + c * 8];
      }
#pragma unroll
      for (int mi = 0; mi < MI; ++mi)
#pragma unroll
        for (int ni = 0; ni < 4; ++ni)
          acc[mi][ni] = __builtin_amdgcn_mfma_f32_16x16x32_bf16(
              av[mi], bfrag[ni], acc[mi][ni], 0, 0, 0);
    }
  }

  // epilogue: C/D layout col = lane&15, row = (lane>>4)*4 + reg
#pragma unroll
  for (int mi = 0; mi < MI; ++mi) {
#pragma unroll
    for (int ni = 0; ni < 4; ++ni) {
      const int col = n0 + wn + ni * 16 + fr;
      float bias_v = 0.0f;
      if (HAS_BIAS == 1) bias_v = bias[sBiasz * z + col];
      if (ADDR_MODE == 7) {                  // z=b*4+h -> Bt_b[n=row][h*512+col]
        const int b = z >> 2, h = z & 3;
#pragma unroll
        for (int r = 0; r < 4; ++r) {
          const int row = m0 + wm + mi * 16 + fq * 4 + r;
          ((bf16*)Cout)[((long)(b * 512 + row)) * 2048 + h * 512 + col] =
              (bf16)(acc[mi][ni][r] + bias_v);
        }
      } else {
#pragma unroll
        for (int r = 0; r < 4; ++r) {
          const int row = m0 + wm + mi * 16 + fq * 4 + r;
          float v = acc[mi][ni][r] + bias_v;
          if (DO_SELU) v = v > 0.0f ? 1.0507009873554805f * v
                                    : 1.7580993408473766f * (__expf(v) - 1.0f);
          long addr = sCz * z + (long)row * N + col;
          if (F32OUT) ((float*)Cout)[addr] = v;
          else        ((bf16*)Cout)[addr] = (bf16)v;
        }
      }
    }
  }
}

// ---------------- merged Q/K/V projection GEMM (3072 blocks, uniform segments) ----------
// seg s: out[b,s,4e+h] = A_s . Bt_s + bias_s (interleaved), coalesced writes.
__global__ void __launch_bounds__(256, 2) gemm_qkv(
    const bf16* __restrict__ Aq, const bf16* __restrict__ Aenc,
    const bf16* __restrict__ BQ, const bf16* __restrict__ BK,
    const bf16* __restrict__ BV,
    const float* __restrict__ bq, const float* __restrict__ bk,
    const float* __restrict__ bv,
    bf16* __restrict__ qlog, bf16* __restrict__ klog, bf16* __restrict__ vlog) {
  __shared__ __align__(16) bf16 lA[128 * 64];
  __shared__ __align__(16) bf16 lB[128 * 64];
  const int id = blockIdx.x;
  const int seg = id >> 10, sid = id & 1023;
  const int xcd = sid & 7, r = sid >> 3;
  const int x = r & 15, y = xcd + 8 * (r >> 4);
  const bf16 *A, *Bt; bf16* out; const float* bias;
  if (seg == 0)      { A = Aq;   Bt = BQ; out = qlog; bias = bq; }
  else if (seg == 1) { A = Aenc; Bt = BK; out = klog; bias = bk; }
  else               { A = Aenc; Bt = BV; out = vlog; bias = bv; }
  const int K = 512;
  const int m0 = y * 128, n0 = x * 128;
  const int t = threadIdx.x;
  const int lane = t & 63, wave = t >> 6;
  const int srow = t >> 3, pch = t & 7, lch = pch ^ (srow & 7);
  const bf16* Ag = A  + (long)(m0 + srow) * K + lch * 8;
  const bf16* Bg = Bt + (long)(n0 + srow) * K + lch * 8;
  bf16* lAp = lA + srow * 64 + pch * 8;
  bf16* lBp = lB + srow * 64 + pch * 8;
  const int wm = (wave >> 1) * 64, wn = (wave & 1) * 64;
  const int fr = lane & 15, fq = lane >> 4;

  f32x4 acc[4][4] = {};
  for (int k0 = 0; k0 < K; k0 += 64) {
    __syncthreads();
#pragma unroll
    for (int i = 0; i < 4; ++i) {
      async16(Ag + k0 + (long)(32 * i) * K, lAp + 32 * i * 64);
      async16(Bg + k0 + (long)(32 * i) * K, lBp + 32 * i * 64);
    }
    __syncthreads();
#pragma unroll
    for (int kk = 0; kk < 2; ++kk) {
      bf16x8 av[4], bfrag[4];
#pragma unroll
      for (int mi = 0; mi < 4; ++mi) {
        int rr = wm + mi * 16 + fr;
        int c = (kk * 4 + fq) ^ (rr & 7);
        av[mi] = *(const bf16x8*)&lA[rr * 64 + c * 8];
      }
#pragma unroll
      for (int ni = 0; ni < 4; ++ni) {
        int rr = wn + ni * 16 + fr;
        int c = (kk * 4 + fq) ^ (rr & 7);
        bfrag[ni] = *(const bf16x8*)&lB[rr * 64 + c * 8];
      }
#pragma unroll
      for (int mi = 0; mi < 4; ++mi)
#pragma unroll
        for (int ni = 0; ni < 4; ++ni)
          acc[mi][ni] = __builtin_amdgcn_mfma_f32_16x16x32_bf16(
              av[mi], bfrag[ni], acc[mi][ni], 0, 0, 0);
    }
  }

#pragma unroll
  for (int mi = 0; mi < 4; ++mi) {
#pragma unroll
    for (int ni = 0; ni < 4; ++ni) {
      const int col = n0 + wn + ni * 16 + fr;
      const float bias_v = bias[(col & 3) * 512 + (col >> 2)];
#pragma unroll
      for (int r = 0; r < 4; ++r) {
        const int row = m0 + wm + mi * 16 + fq * 4 + r;
        out[(long)row * 2048 + col] = (bf16)(acc[mi][ni][r] + bias_v);
      }
    }
  }
}

// ---------------- launcher ----------------
extern "C" void kernel_launch(void* const* d_in, const int* in_sizes, int n_in,
                              void* d_out, int out_size, void* d_ws, size_t ws_size,
                              hipStream_t stream) {
  (void)in_sizes; (void)n_in; (void)out_size; (void)ws_size;
  const float* x_enc = (const float*)d_in[0];
  const float* x_dec = (const float*)d_in[1];
  const float* Wq = (const float*)d_in[2];
  const float* bq = (const float*)d_in[3];
  const float* Wk = (const float*)d_in[4];
  const float* bk = (const float*)d_in[5];
  const float* Wv = (const float*)d_in[6];
  const float* bv = (const float*)d_in[7];
  const float* Wo = (const float*)d_in[8];
  const float* bo = (const float*)d_in[9];
  const float* g1 = (const float*)d_in[10];
  const float* be1 = (const float*)d_in[11];
  const float* g2 = (const float*)d_in[12];
  const float* be2 = (const float*)d_in[13];
  const float* W1 = (const float*)d_in[14];
  const float* b1 = (const float*)d_in[15];
  const float* W2 = (const float*)d_in[16];
  const float* b2 = (const float*)d_in[17];
  const float* g3 = (const float*)d_in[18];
  const float* be3 = (const float*)d_in[19];

  char* ws = (char*)d_ws;
  const size_t MB = 1u << 20;
  // time-disjoint aliasing, peak 255 MiB
  bf16*  qlog   = (bf16*) (ws + 0);        // dead after softmax
  bf16*  midb   = (bf16*) (ws + 0);        // W1 out
  bf16*  klog   = (bf16*) (ws + 32 * MB);  // dead after softmax
  bf16*  attn_b = (bf16*) (ws + 32 * MB);  // attn GEMM out
  bf16*  vlog   = (bf16*) (ws + 64 * MB);  // dead after softmax
  bf16*  gc     = (bf16*) (ws + 64 * MB);  // gc out
  bf16*  ff_b   = (bf16*) (ws + 72 * MB);  // W2 out
  bf16*  Atrig2 = (bf16*) (ws + 96 * MB);  // [96,101) dead after CS GEMM
  bf16*  Ttrig  = (bf16*) (ws + 101 * MB); // [101,102) dead after Yt GEMM
  bf16*  CSb    = (bf16*) (ws + 102 * MB); // [102,112) dead after LN1
  bf16*  qs2    = (bf16*) (ws + 96 * MB);  // [96,128) written by softmax
  bf16*  xenc_b = (bf16*) (ws + 128 * MB); // [128,136) dead after qkv
  bf16*  BtQ    = (bf16*) (ws + 136 * MB); // [136,142) dead after qkv
  bf16*  BtK    = (bf16*) (ws + 138 * MB);
  bf16*  BtV    = (bf16*) (ws + 140 * MB);
  bf16*  ksT    = (bf16*) (ws + 128 * MB); // [128,160) written by softmax
  bf16*  vsT    = (bf16*) (ws + 160 * MB); // [160,192)
  bf16*  xd_b   = (bf16*) (ws + 192 * MB); // [192,200)
  bf16*  x2_b   = (bf16*) (ws + 200 * MB); // [200,208)
  bf16*  gwT    = (bf16*) (ws + 208 * MB); // [208,216)
  bf16*  Yt     = (bf16*) (ws + 216 * MB); // [216,232) dead after fold
  bf16*  Yf2    = (bf16*) (ws + 232 * MB); // [232,241) dead after CS GEMM
  bf16*  WoTh   = (bf16*) (ws + 241 * MB); // [241,243)
  bf16*  W1T    = (bf16*) (ws + 243 * MB);
  bf16*  W2T    = (bf16*) (ws + 245 * MB);
  bf16*  xdec_b = (bf16*) (ws + 247 * MB); // [247,255) dead after Yt GEMM

  // --- prep (one launch) ---
  prep_all<<<50752, 256, 0, stream>>>(x_dec, x_enc, Ttrig, Atrig2, xdec_b, xenc_b,
                                      Wq, Wk, Wv, Wo, W1, W2,
                                      BtQ, BtK, BtV, WoTh, W1T, W2T);

  // --- Fourier mixing ---
  // Yt[b][2jj+p][s] = (x_dec[b] . C2/S2)  (K=512); group-by-x: XCD owns B col-tiles
  gemm_bt<128, 0, 0, 0, 0, 3><<<512, 256, 0, stream>>>(
      Ttrig, xdec_b, nullptr, Yt, 2048, 512, 0L, 1048576L, 0L, 2097152L, 16, 8, 32);
  fold_y<<<17408, 256, 0, stream>>>(Yt, Yf2);
  // CS GEMM: z=0..3 cos (A slice 0), z=4..7 sin (A slice 1); M=1152, K=1088
  gemm_bt<64, 0, 0, 0, 0, 2, 2><<<576, 256, 0, stream>>>(
      Atrig2, Yf2, nullptr, CSb, 512, 1088, 1253376L, 557056L, 0L, 589824L, 8, 9, 72);
  ln1_kernel<<<8192, 256, 0, stream>>>(x_dec, CSb, g1, be1, xd_b);

  // --- attention ---
  gemm_qkv<<<3072, 256, 0, stream>>>(xd_b, xenc_b, BtQ, BtK, BtV,
                                     bq, bk, bv, qlog, klog, vlog);
  softmax_qkv<<<18432, 256, 0, stream>>>(qlog, qs2, klog, ksT, vlog, vsT);
  gemm_bt<64, 0, 0, 0, 0, 2><<<512, 256, 0, stream>>>(     // gc[z][d,e] (K=2048)
      ksT, vsT, nullptr, gc, 512, 2048, 1048576L, 1048576L, 0L, 262144L, 8, 4, 32);
  gemm_bt<64, 7, 0, 0, 0, 2, 1><<<512, 256, 0, stream>>>(  // gwT: WoTh[h] . gc[z]^T
      WoTh, gc, nullptr, gwT, 512, 512, 262144L, 262144L, 0L, 0L, 8, 4, 32);
  gemm_bt<64, 0, 1, 0, 0, 1><<<512, 256, 0, stream>>>(     // attn = qs2 . gwT^T + bo
      qs2, gwT, bo, attn_b, 512, 2048, 4194304L, 1048576L, 0L, 1048576L, 8, 16, 32);
  ln_kernel<bf16, bf16, 1, 0><<<8192, 256, 0, stream>>>(
      xd_b, attn_b, g2, be2, x2_b, nullptr);

  // --- FFN ---
  gemm_bt<128, 0, 1, 1, 0, 1><<<1024, 256, 0, stream>>>(
      x2_b, W1T, b1, midb, 2048, 512, 0L, 0L, 0L, 0L, 16, 64, 16);
  gemm_bt<64, 0, 1, 0, 0, 1><<<512, 256, 0, stream>>>(
      midb, W2T, b2, ff_b, 512, 2048, 0L, 0L, 0L, 0L, 8, 64, 8);
  ln_kernel<bf16, bf16, 0, 1><<<8192, 256, 0, stream>>>(
      x2_b, ff_b, g3, be3, nullptr, (float*)d_out);
}